// Round 1
// baseline (29481.204 us; speedup 1.0000x reference)
//
#include <hip/hip_runtime.h>
#include <hip/hip_bf16.h>
#include <math.h>

#define TT 1024
#define DD 1024
#define NH 16
#define HDIM 64
#define NB 2
#define NL 12
#define RR 32
#define MM (NB * TT)  // 2048

// ---------------------------------------------------------------- embed
__global__ __launch_bounds__(256) void embed_k(const int* __restrict__ ids,
                                               const float* __restrict__ wte,
                                               const float* __restrict__ wpe,
                                               float* __restrict__ h) {
  const int i = blockIdx.x * 256 + threadIdx.x;  // over MM*DD
  const int row = i >> 10;
  const int d = i & 1023;
  const int t = row & (TT - 1);
  const int id = ids[row];
  h[i] = wte[(size_t)id * DD + d] + wpe[(size_t)t * DD + d];
}

// ---------------------------------------------------------------- layernorm
__global__ __launch_bounds__(256) void ln_k(const float* __restrict__ x,
                                            const float* __restrict__ w,
                                            const float* __restrict__ b,
                                            float* __restrict__ out) {
  const int row = blockIdx.x;
  const float* xr = x + (size_t)row * DD;
  float v[4];
  float s = 0.f, ss = 0.f;
#pragma unroll
  for (int k = 0; k < 4; ++k) {
    v[k] = xr[threadIdx.x + k * 256];
    s += v[k];
    ss += v[k] * v[k];
  }
#pragma unroll
  for (int off = 32; off > 0; off >>= 1) {
    s += __shfl_down(s, off);
    ss += __shfl_down(ss, off);
  }
  __shared__ float rs[4], rss[4];
  const int wid = threadIdx.x >> 6;
  if ((threadIdx.x & 63) == 0) { rs[wid] = s; rss[wid] = ss; }
  __syncthreads();
  s = rs[0] + rs[1] + rs[2] + rs[3];
  ss = rss[0] + rss[1] + rss[2] + rss[3];
  const float mean = s * (1.f / DD);
  const float var = ss * (1.f / DD) - mean * mean;
  const float rstd = rsqrtf(var + 1e-5f);
  float* orow = out + (size_t)row * DD;
#pragma unroll
  for (int k = 0; k < 4; ++k) {
    const int c = threadIdx.x + k * 256;
    orow[c] = (v[k] - mean) * rstd * w[c] + b[c];
  }
}

// ---------------------------------------------------------------- fp32 GEMM
// C[m,n] = scale * sum_k A[m,k]*W[n,k] + bias[n] + add1[m,n] + add2[m,n]
// A: [M,K] row-major; W: [N,K] row-major (i.e. x @ W^T). M % 64 == 0, K % 16 == 0.
__global__ __launch_bounds__(256) void gemm_k(const float* __restrict__ A,
                                              const float* __restrict__ W,
                                              const float* __restrict__ bias,
                                              const float* __restrict__ add1,
                                              const float* __restrict__ add2,
                                              float* __restrict__ C,
                                              int M, int N, int K, float scale) {
  __shared__ float As[16][65];
  __shared__ float Ws[16][65];
  const int tid = threadIdx.x;
  const int tx = tid & 15, ty = tid >> 4;
  const int bm = blockIdx.y * 64, bn = blockIdx.x * 64;
  const int lr = tid >> 2;        // 0..63
  const int lc = (tid & 3) * 4;   // 0,4,8,12
  float acc[4][4] = {};
  for (int k0 = 0; k0 < K; k0 += 16) {
    const float4 av = *(const float4*)(A + (size_t)(bm + lr) * K + k0 + lc);
    float4 wv = make_float4(0.f, 0.f, 0.f, 0.f);
    if (bn + lr < N) wv = *(const float4*)(W + (size_t)(bn + lr) * K + k0 + lc);
    __syncthreads();
    As[lc + 0][lr] = av.x; As[lc + 1][lr] = av.y;
    As[lc + 2][lr] = av.z; As[lc + 3][lr] = av.w;
    Ws[lc + 0][lr] = wv.x; Ws[lc + 1][lr] = wv.y;
    Ws[lc + 2][lr] = wv.z; Ws[lc + 3][lr] = wv.w;
    __syncthreads();
#pragma unroll
    for (int kk = 0; kk < 16; ++kk) {
      float a[4], bb[4];
#pragma unroll
      for (int i = 0; i < 4; ++i) a[i] = As[kk][ty + i * 16];
#pragma unroll
      for (int j = 0; j < 4; ++j) bb[j] = Ws[kk][tx + j * 16];
#pragma unroll
      for (int i = 0; i < 4; ++i)
#pragma unroll
        for (int j = 0; j < 4; ++j) acc[i][j] = fmaf(a[i], bb[j], acc[i][j]);
    }
  }
#pragma unroll
  for (int i = 0; i < 4; ++i) {
    const int row = bm + ty + i * 16;
#pragma unroll
    for (int j = 0; j < 4; ++j) {
      const int col = bn + tx + j * 16;
      if (col < N) {
        float v = acc[i][j] * scale;
        if (bias) v += bias[col];
        const size_t idx = (size_t)row * N + col;
        if (add1) v += add1[idx];
        if (add2) v += add2[idx];
        C[idx] = v;
      }
    }
  }
}

// ---------------------------------------------------------------- GELU (exact, erf)
__global__ __launch_bounds__(256) void gelu_k(float* __restrict__ x) {
  const int i = blockIdx.x * 256 + threadIdx.x;
  const float v = x[i];
  x[i] = 0.5f * v * (1.f + erff(v * 0.70710678118654752f));
}

// ---------------------------------------------------------------- causal flash attention (fp32)
// qkv: [B, T, 3*D]; out: [B*T, D]. One 64-thread block per (q-tile of 64 rows, b*h).
__global__ __launch_bounds__(64) void attn_k(const float* __restrict__ qkv,
                                             float* __restrict__ out) {
  const int qt = blockIdx.x;   // 0..15
  const int bh = blockIdx.y;   // 0..31
  const int b = bh >> 4;
  const int hh = bh & 15;
  const int tid = threadIdx.x;
  const int tq = qt * 64 + tid;
  const float* base = qkv + (size_t)b * TT * 3 * DD;
  __shared__ float Kt[64][72];
  __shared__ float Vt[64][72];
  __shared__ float Ss[64][65];  // per-thread private score scratch (row tid)
  float q[64], oacc[64];
  {
    const float* qr = base + (size_t)tq * (3 * DD) + hh * 64;
#pragma unroll
    for (int d = 0; d < 64; d += 4) {
      float4 v = *(const float4*)(qr + d);
      q[d] = v.x; q[d + 1] = v.y; q[d + 2] = v.z; q[d + 3] = v.w;
    }
  }
#pragma unroll
  for (int d = 0; d < 64; ++d) oacc[d] = 0.f;
  float mrun = -1e30f, lrun = 0.f;
  const int r0 = tid >> 4;        // 0..3
  const int c0 = (tid & 15) * 4;  // 0..60
  for (int kt = 0; kt <= qt; ++kt) {
    __syncthreads();
#pragma unroll
    for (int it = 0; it < 16; ++it) {
      const int row = it * 4 + r0;
      const float* kr = base + (size_t)(kt * 64 + row) * (3 * DD) + DD + hh * 64 + c0;
      *(float4*)&Kt[row][c0] = *(const float4*)kr;
      *(float4*)&Vt[row][c0] = *(const float4*)(kr + DD);
    }
    __syncthreads();
    const int jmax = (kt == qt) ? tid : 63;
    float mt = -1e30f;
    for (int j = 0; j <= jmax; ++j) {
      float s = 0.f;
#pragma unroll
      for (int d = 0; d < 64; ++d) s += q[d] * Kt[j][d];
      s *= 0.125f;
      Ss[tid][j] = s;
      mt = fmaxf(mt, s);
    }
    const float mn = fmaxf(mrun, mt);
    const float corr = expf(mrun - mn);
    lrun *= corr;
#pragma unroll
    for (int d = 0; d < 64; ++d) oacc[d] *= corr;
    for (int j = 0; j <= jmax; ++j) {
      const float p = expf(Ss[tid][j] - mn);
      lrun += p;
#pragma unroll
      for (int d = 0; d < 64; ++d) oacc[d] = fmaf(p, Vt[j][d], oacc[d]);
    }
    mrun = mn;
  }
  const float inv = 1.f / lrun;
  float* orow = out + (size_t)(b * TT + tq) * DD + hh * 64;
#pragma unroll
  for (int d = 0; d < 64; d += 4) {
    float4 v = make_float4(oacc[d] * inv, oacc[d + 1] * inv, oacc[d + 2] * inv,
                           oacc[d + 3] * inv);
    *(float4*)(orow + d) = v;
  }
}

// ---------------------------------------------------------------- host
extern "C" void kernel_launch(void* const* d_in, const int* in_sizes, int n_in,
                              void* d_out, int out_size, void* d_ws, size_t ws_size,
                              hipStream_t stream) {
  (void)in_sizes; (void)n_in; (void)out_size; (void)ws_size;
  const int* ids = (const int*)d_in[0];
  const float* wte = (const float*)d_in[1];
  const float* wpe = (const float*)d_in[2];
  const float* ln1w = (const float*)d_in[3];
  const float* ln1b = (const float*)d_in[4];
  const float* attnw = (const float*)d_in[5];
  const float* attnb = (const float*)d_in[6];
  const float* attnla = (const float*)d_in[7];
  const float* attnlb = (const float*)d_in[8];
  const float* projw = (const float*)d_in[9];
  const float* projb = (const float*)d_in[10];
  const float* projla = (const float*)d_in[11];
  const float* projlb = (const float*)d_in[12];
  const float* ln2w = (const float*)d_in[13];
  const float* ln2b = (const float*)d_in[14];
  const float* fcw = (const float*)d_in[15];
  const float* fcb = (const float*)d_in[16];
  const float* fcla = (const float*)d_in[17];
  const float* fclb = (const float*)d_in[18];
  const float* mpw = (const float*)d_in[19];
  const float* mpb = (const float*)d_in[20];
  const float* mpla = (const float*)d_in[21];
  const float* mplb = (const float*)d_in[22];
  const float* lnfw = (const float*)d_in[23];
  const float* lnfb = (const float*)d_in[24];

  float* h = (float*)d_ws;                 // [2048,1024]
  float* x = h + (size_t)MM * DD;          // [2048,1024]
  float* hqkv = x + (size_t)MM * DD;       // [2048,3072]
  float* ho = hqkv + (size_t)MM * 3 * DD;  // [2048,1024]
  float* t1 = ho + (size_t)MM * DD;        // [2048,32]
  float* hd1 = t1 + (size_t)MM * RR;       // [2048,1024]
  float* hm1 = hd1 + (size_t)MM * DD;      // [2048,4096]

  dim3 blk(256);
  auto gemm = [&](const float* A, const float* W, const float* bias,
                  const float* add1, const float* add2, float* C, int M, int N,
                  int K, float scale) {
    dim3 grid((N + 63) / 64, M / 64);
    hipLaunchKernelGGL(gemm_k, grid, blk, 0, stream, A, W, bias, add1, add2, C,
                       M, N, K, scale);
  };

  hipLaunchKernelGGL(embed_k, dim3(MM * DD / 256), blk, 0, stream, ids, wte, wpe, h);

  for (int l = 0; l < NL; ++l) {
    const float* aw = attnw + (size_t)l * 3 * DD * DD;
    const float* ab = attnb + (size_t)l * 3 * DD;
    const float* ala = attnla + (size_t)l * RR * DD;
    const float* alb = attnlb + (size_t)l * 3 * DD * RR;
    const float* pw = projw + (size_t)l * DD * DD;
    const float* pb = projb + (size_t)l * DD;
    const float* pla = projla + (size_t)l * RR * DD;
    const float* plb = projlb + (size_t)l * DD * RR;
    const float* fw = fcw + (size_t)l * 4 * DD * DD;
    const float* fb = fcb + (size_t)l * 4 * DD;
    const float* fla = fcla + (size_t)l * RR * DD;
    const float* flb = fclb + (size_t)l * 4 * DD * RR;
    const float* mw = mpw + (size_t)l * DD * 4 * DD;
    const float* mb = mpb + (size_t)l * DD;
    const float* mla = mpla + (size_t)l * RR * 4 * DD;
    const float* mlb = mplb + (size_t)l * DD * RR;

    // x = LN1(h)
    hipLaunchKernelGGL(ln_k, dim3(MM), blk, 0, stream, h, ln1w + (size_t)l * DD,
                       ln1b + (size_t)l * DD, x);
    // qkv = x @ aw^T + ab ; += 2 * (x @ ala^T) @ alb^T
    gemm(x, aw, ab, nullptr, nullptr, hqkv, MM, 3 * DD, DD, 1.f);
    gemm(x, ala, nullptr, nullptr, nullptr, t1, MM, RR, DD, 1.f);
    gemm(t1, alb, nullptr, hqkv, nullptr, hqkv, MM, 3 * DD, RR, 2.f);
    // o = attention(qkv)
    hipLaunchKernelGGL(attn_k, dim3(TT / 64, NB * NH), dim3(64), 0, stream, hqkv, ho);
    // h = h + o @ pw^T + pb + 2 * (o @ pla^T) @ plb^T
    gemm(ho, pw, pb, nullptr, nullptr, hd1, MM, DD, DD, 1.f);
    gemm(ho, pla, nullptr, nullptr, nullptr, t1, MM, RR, DD, 1.f);
    gemm(t1, plb, nullptr, hd1, h, h, MM, DD, RR, 2.f);
    // x = LN2(h)
    hipLaunchKernelGGL(ln_k, dim3(MM), blk, 0, stream, h, ln2w + (size_t)l * DD,
                       ln2b + (size_t)l * DD, x);
    // m = gelu(x @ fw^T + fb + 2 * (x @ fla^T) @ flb^T)
    gemm(x, fw, fb, nullptr, nullptr, hm1, MM, 4 * DD, DD, 1.f);
    gemm(x, fla, nullptr, nullptr, nullptr, t1, MM, RR, DD, 1.f);
    gemm(t1, flb, nullptr, hm1, nullptr, hm1, MM, 4 * DD, RR, 2.f);
    hipLaunchKernelGGL(gelu_k, dim3(MM * 4 * DD / 256), blk, 0, stream, hm1);
    // h = h + m @ mw^T + mb + 2 * (m @ mla^T) @ mlb^T
    gemm(hm1, mw, mb, nullptr, nullptr, hd1, MM, DD, 4 * DD, 1.f);
    gemm(hm1, mla, nullptr, nullptr, nullptr, t1, MM, RR, 4 * DD, 1.f);
    gemm(t1, mlb, nullptr, hd1, h, h, MM, DD, RR, 2.f);
  }

  hipLaunchKernelGGL(ln_k, dim3(MM), blk, 0, stream, h, lnfw, lnfb, (float*)d_out);
}

// Round 2
// 6434.534 us; speedup vs baseline: 4.5817x; 4.5817x over previous
//
#include <hip/hip_runtime.h>
#include <math.h>

#define TT 1024
#define DD 1024
#define NH 16
#define NB 2
#define NL 12
#define RR 32
#define MM (NB * TT)  // 2048

typedef __attribute__((ext_vector_type(8))) short bf16x8;
typedef __attribute__((ext_vector_type(4))) float f32x4;

__device__ __forceinline__ unsigned short f2bf(float f) {
  unsigned int u = __float_as_uint(f);
  u = (u + 0x7FFFu + ((u >> 16) & 1u)) >> 16;
  return (unsigned short)u;
}

typedef __attribute__((address_space(1))) void gvoid;
typedef __attribute__((address_space(3))) void lvoid;
__device__ __forceinline__ void gload_lds16(const void* g, void* l) {
  __builtin_amdgcn_global_load_lds((gvoid*)g, (lvoid*)l, 16, 0, 0);
}

// ---------------------------------------------------------------- embed
__global__ __launch_bounds__(256) void embed_k(const int* __restrict__ ids,
                                               const float* __restrict__ wte,
                                               const float* __restrict__ wpe,
                                               float* __restrict__ h) {
  const int i = blockIdx.x * 256 + threadIdx.x;
  const int row = i >> 10;
  const int d = i & 1023;
  const int t = row & (TT - 1);
  const int id = ids[row];
  h[i] = wte[(size_t)id * DD + d] + wpe[(size_t)t * DD + d];
}

// ---------------------------------------------------------------- layernorm (fp32 in, bf16 out)
__global__ __launch_bounds__(256) void ln_bf_k(const float* __restrict__ x,
                                               const float* __restrict__ w,
                                               const float* __restrict__ b,
                                               unsigned short* __restrict__ out) {
  const int row = blockIdx.x;
  const float* xr = x + (size_t)row * DD;
  const float4 v = *(const float4*)(xr + threadIdx.x * 4);
  float s = v.x + v.y + v.z + v.w;
  float ss = v.x * v.x + v.y * v.y + v.z * v.z + v.w * v.w;
#pragma unroll
  for (int off = 32; off > 0; off >>= 1) {
    s += __shfl_down(s, off);
    ss += __shfl_down(ss, off);
  }
  __shared__ float rs[4], rss[4];
  const int wid = threadIdx.x >> 6;
  if ((threadIdx.x & 63) == 0) { rs[wid] = s; rss[wid] = ss; }
  __syncthreads();
  s = rs[0] + rs[1] + rs[2] + rs[3];
  ss = rss[0] + rss[1] + rss[2] + rss[3];
  const float mean = s * (1.f / DD);
  const float var = ss * (1.f / DD) - mean * mean;
  const float rstd = rsqrtf(var + 1e-5f);
  const float4 wv = *(const float4*)(w + threadIdx.x * 4);
  const float4 bv = *(const float4*)(b + threadIdx.x * 4);
  ushort4 o;
  o.x = f2bf((v.x - mean) * rstd * wv.x + bv.x);
  o.y = f2bf((v.y - mean) * rstd * wv.y + bv.y);
  o.z = f2bf((v.z - mean) * rstd * wv.z + bv.z);
  o.w = f2bf((v.w - mean) * rstd * wv.w + bv.w);
  *(ushort4*)(out + (size_t)row * DD + threadIdx.x * 4) = o;
}

// final layernorm fp32 out
__global__ __launch_bounds__(256) void ln_f_k(const float* __restrict__ x,
                                              const float* __restrict__ w,
                                              const float* __restrict__ b,
                                              float* __restrict__ out) {
  const int row = blockIdx.x;
  const float* xr = x + (size_t)row * DD;
  const float4 v = *(const float4*)(xr + threadIdx.x * 4);
  float s = v.x + v.y + v.z + v.w;
  float ss = v.x * v.x + v.y * v.y + v.z * v.z + v.w * v.w;
#pragma unroll
  for (int off = 32; off > 0; off >>= 1) {
    s += __shfl_down(s, off);
    ss += __shfl_down(ss, off);
  }
  __shared__ float rs[4], rss[4];
  const int wid = threadIdx.x >> 6;
  if ((threadIdx.x & 63) == 0) { rs[wid] = s; rss[wid] = ss; }
  __syncthreads();
  s = rs[0] + rs[1] + rs[2] + rs[3];
  ss = rss[0] + rss[1] + rss[2] + rss[3];
  const float mean = s * (1.f / DD);
  const float var = ss * (1.f / DD) - mean * mean;
  const float rstd = rsqrtf(var + 1e-5f);
  const float4 wv = *(const float4*)(w + threadIdx.x * 4);
  const float4 bv = *(const float4*)(b + threadIdx.x * 4);
  float4 o;
  o.x = (v.x - mean) * rstd * wv.x + bv.x;
  o.y = (v.y - mean) * rstd * wv.y + bv.y;
  o.z = (v.z - mean) * rstd * wv.z + bv.z;
  o.w = (v.w - mean) * rstd * wv.w + bv.w;
  *(float4*)(out + (size_t)row * DD + threadIdx.x * 4) = o;
}

// ---------------------------------------------------------------- LoRA fold: out = bf16(W + 2*B@A)
// W [N,K] fp32, A [R=32,K] fp32, B [N,R] fp32, out [N,K] bf16.
// block: 256 thr; tile 16 n x 256 k. grid (K/256, N/16)
__global__ __launch_bounds__(256) void fusew_k(const float* __restrict__ W,
                                               const float* __restrict__ Al,
                                               const float* __restrict__ Bl,
                                               unsigned short* __restrict__ out,
                                               int N, int K) {
  __shared__ float As[32][260];
  const int tid = threadIdx.x;
  const int k0 = blockIdx.x * 256;
  const int n0 = blockIdx.y * 16;
#pragma unroll
  for (int i = 0; i < 8; ++i) {
    const int f4 = tid + i * 256;  // 0..2047 float4s over [32][256]
    const int r = f4 >> 6;
    const int c = (f4 & 63) * 4;
    *(float4*)&As[r][c] = *(const float4*)(Al + (size_t)r * K + k0 + c);
  }
  const int nl = tid >> 4;          // 0..15
  const int kl = (tid & 15) * 4;    // 0..60
  float br[32];
  {
    const float* bp = Bl + (size_t)(n0 + nl) * RR;
#pragma unroll
    for (int r = 0; r < 32; r += 4) {
      const float4 v = *(const float4*)(bp + r);
      br[r] = 2.f * v.x; br[r + 1] = 2.f * v.y;
      br[r + 2] = 2.f * v.z; br[r + 3] = 2.f * v.w;
    }
  }
  float acc[16];
  const float* wp = W + (size_t)(n0 + nl) * K + k0;
#pragma unroll
  for (int j = 0; j < 4; ++j) {
    const float4 v = *(const float4*)(wp + kl + j * 64);
    acc[j * 4 + 0] = v.x; acc[j * 4 + 1] = v.y;
    acc[j * 4 + 2] = v.z; acc[j * 4 + 3] = v.w;
  }
  __syncthreads();
#pragma unroll
  for (int r = 0; r < 32; ++r) {
    const float bb = br[r];
#pragma unroll
    for (int j = 0; j < 4; ++j) {
      const float4 a = *(const float4*)&As[r][kl + j * 64];
      acc[j * 4 + 0] = fmaf(bb, a.x, acc[j * 4 + 0]);
      acc[j * 4 + 1] = fmaf(bb, a.y, acc[j * 4 + 1]);
      acc[j * 4 + 2] = fmaf(bb, a.z, acc[j * 4 + 2]);
      acc[j * 4 + 3] = fmaf(bb, a.w, acc[j * 4 + 3]);
    }
  }
  unsigned short* op = out + (size_t)(n0 + nl) * K + k0;
#pragma unroll
  for (int j = 0; j < 4; ++j) {
    ushort4 u;
    u.x = f2bf(acc[j * 4 + 0]); u.y = f2bf(acc[j * 4 + 1]);
    u.z = f2bf(acc[j * 4 + 2]); u.w = f2bf(acc[j * 4 + 3]);
    *(ushort4*)(op + kl + j * 64) = u;
  }
}

// ---------------------------------------------------------------- bf16 MFMA GEMM (m97 structure)
// C[m,n] = sum_k A[m,k]*Wt[n,k] + bias[n] (+res) ; MODE 0: fp32 out, 1: fp32 out + res, 2: gelu->bf16
#define BM 128
#define BN 128
#define BK 32
template <int MODE>
__global__ __launch_bounds__(256) void gemm_bf16(const unsigned short* __restrict__ A,
                                                 const unsigned short* __restrict__ Wt,
                                                 const float* __restrict__ bias,
                                                 const float* __restrict__ res,
                                                 float* __restrict__ Cf,
                                                 unsigned short* __restrict__ Cb,
                                                 int M, int N, int K) {
  __shared__ unsigned short As[BM * BK];
  __shared__ unsigned short Bs[BN * BK];
  const int tid = threadIdx.x;
  const int w = tid >> 6, l = tid & 63;
  const int bm = blockIdx.y * BM, bn = blockIdx.x * BN;
  const int wr = w >> 1, wc = w & 1;
  f32x4 acc[4][4] = {};
  const int srow = w * 32 + (l >> 2);
  const int scol = (l & 3) * 8;
  const unsigned short* ga = A + (size_t)(bm + srow) * K + scol;
  const unsigned short* gb = Wt + (size_t)(bn + srow) * K + scol;
  char* lA = (char*)As + w * 2048;
  char* lB = (char*)Bs + w * 2048;
  const int kb = (l >> 4) * 8;
  const int rA = wr * 64 + (l & 15);
  const int rB = wc * 64 + (l & 15);
  for (int k0 = 0; k0 < K; k0 += BK) {
    __syncthreads();
    gload_lds16(ga + k0, lA);
    gload_lds16(ga + k0 + (size_t)16 * K, lA + 1024);
    gload_lds16(gb + k0, lB);
    gload_lds16(gb + k0 + (size_t)16 * K, lB + 1024);
    __syncthreads();
    bf16x8 af[4], bf[4];
#pragma unroll
    for (int i = 0; i < 4; ++i) {
      af[i] = *(const bf16x8*)(As + (rA + i * 16) * BK + kb);
      bf[i] = *(const bf16x8*)(Bs + (rB + i * 16) * BK + kb);
    }
#pragma unroll
    for (int i = 0; i < 4; ++i)
#pragma unroll
      for (int j = 0; j < 4; ++j)
        acc[i][j] = __builtin_amdgcn_mfma_f32_16x16x32_bf16(af[i], bf[j], acc[i][j], 0, 0, 0);
  }
  const int cr = (l >> 4) * 4;
  const int cc = l & 15;
#pragma unroll
  for (int i = 0; i < 4; ++i) {
    const int gr0 = bm + wr * 64 + i * 16 + cr;
#pragma unroll
    for (int j = 0; j < 4; ++j) {
      const int gc = bn + wc * 64 + j * 16 + cc;
      const float bv = bias[gc];
#pragma unroll
      for (int r = 0; r < 4; ++r) {
        float v = acc[i][j][r] + bv;
        const size_t idx = (size_t)(gr0 + r) * N + gc;
        if (MODE == 1) v += res[idx];
        if (MODE == 2) {
          v = 0.5f * v * (1.f + erff(v * 0.70710678118654752f));
          Cb[idx] = f2bf(v);
        } else {
          Cf[idx] = v;
        }
      }
    }
  }
}

// ---------------------------------------------------------------- causal attention, fp32, ILP-optimized
// qkv fp32 [B,T,3D]; out bf16 [B*T, D]. block 128 thr = 2 waves; q-tile 64; thread=(q,d-half).
__device__ __forceinline__ float4 fma4s(float p, float4 v, float4 a) {
  a.x = fmaf(p, v.x, a.x); a.y = fmaf(p, v.y, a.y);
  a.z = fmaf(p, v.z, a.z); a.w = fmaf(p, v.w, a.w);
  return a;
}

__global__ __launch_bounds__(128) void attn2_k(const float* __restrict__ qkv,
                                               unsigned short* __restrict__ out) {
  const int qt = blockIdx.x;   // 0..15
  const int bh = blockIdx.y;   // 0..31
  const int b = bh >> 4, hh = bh & 15;
  const int tid = threadIdx.x;
  const int w = tid >> 6;
  const int l = tid & 63;
  const int qr = (l & 31) + w * 32;  // 0..63
  const int half = l >> 5;
  const int tq = qt * 64 + qr;
  const float* base = qkv + (size_t)b * TT * 3 * DD;
  __shared__ float Kt[64][68];
  __shared__ float Vt[64][68];
  float4 qv[8], oa[8];
  {
    const float* qp = base + (size_t)tq * (3 * DD) + hh * 64 + half * 32;
#pragma unroll
    for (int d4 = 0; d4 < 8; ++d4) {
      float4 v = *(const float4*)(qp + d4 * 4);
      v.x *= 0.125f; v.y *= 0.125f; v.z *= 0.125f; v.w *= 0.125f;
      qv[d4] = v;
      oa[d4] = make_float4(0.f, 0.f, 0.f, 0.f);
    }
  }
  float m = -1e30f, lsum = 0.f;
  const int ntiles = qt + 1;
  const int srow = tid >> 1, sc0 = (tid & 1) * 32;
  for (int kt = 0; kt < ntiles; ++kt) {
    __syncthreads();
    {
      const float* kp = base + (size_t)(kt * 64 + srow) * (3 * DD) + DD + hh * 64 + sc0;
      const float* vp = kp + DD;
#pragma unroll
      for (int c = 0; c < 32; c += 4) {
        *(float4*)&Kt[srow][sc0 + c] = *(const float4*)(kp + c);
        *(float4*)&Vt[srow][sc0 + c] = *(const float4*)(vp + c);
      }
    }
    __syncthreads();
    const int jlim_w = min(64, qt * 64 + w * 32 + 31 - kt * 64 + 1);
    const int jv = tq - kt * 64 + 1;  // per-lane valid count
    for (int j0 = 0; j0 < jlim_w; j0 += 16) {
      float s[16];
#pragma unroll
      for (int jj = 0; jj < 16; jj += 4) {
        const float4* k0p = (const float4*)&Kt[j0 + jj + 0][half * 32];
        const float4* k1p = (const float4*)&Kt[j0 + jj + 1][half * 32];
        const float4* k2p = (const float4*)&Kt[j0 + jj + 2][half * 32];
        const float4* k3p = (const float4*)&Kt[j0 + jj + 3][half * 32];
        float4 A0 = {0, 0, 0, 0}, A1 = {0, 0, 0, 0}, A2 = {0, 0, 0, 0}, A3 = {0, 0, 0, 0};
#pragma unroll
        for (int d4 = 0; d4 < 8; ++d4) {
          const float4 q4 = qv[d4];
          float4 kv;
          kv = k0p[d4];
          A0.x = fmaf(q4.x, kv.x, A0.x); A0.y = fmaf(q4.y, kv.y, A0.y);
          A0.z = fmaf(q4.z, kv.z, A0.z); A0.w = fmaf(q4.w, kv.w, A0.w);
          kv = k1p[d4];
          A1.x = fmaf(q4.x, kv.x, A1.x); A1.y = fmaf(q4.y, kv.y, A1.y);
          A1.z = fmaf(q4.z, kv.z, A1.z); A1.w = fmaf(q4.w, kv.w, A1.w);
          kv = k2p[d4];
          A2.x = fmaf(q4.x, kv.x, A2.x); A2.y = fmaf(q4.y, kv.y, A2.y);
          A2.z = fmaf(q4.z, kv.z, A2.z); A2.w = fmaf(q4.w, kv.w, A2.w);
          kv = k3p[d4];
          A3.x = fmaf(q4.x, kv.x, A3.x); A3.y = fmaf(q4.y, kv.y, A3.y);
          A3.z = fmaf(q4.z, kv.z, A3.z); A3.w = fmaf(q4.w, kv.w, A3.w);
        }
        s[jj + 0] = (A0.x + A0.y) + (A0.z + A0.w);
        s[jj + 1] = (A1.x + A1.y) + (A1.z + A1.w);
        s[jj + 2] = (A2.x + A2.y) + (A2.z + A2.w);
        s[jj + 3] = (A3.x + A3.y) + (A3.z + A3.w);
      }
#pragma unroll
      for (int i = 0; i < 16; ++i) {
        s[i] += __shfl_xor(s[i], 32);
        if (j0 + i >= jv) s[i] = -1e30f;
      }
      float mt = s[0];
#pragma unroll
      for (int i = 1; i < 16; ++i) mt = fmaxf(mt, s[i]);
      const float mn = fmaxf(m, mt);
      const float corr = __expf(m - mn);
      lsum *= corr;
#pragma unroll
      for (int d4 = 0; d4 < 8; ++d4) {
        oa[d4].x *= corr; oa[d4].y *= corr; oa[d4].z *= corr; oa[d4].w *= corr;
      }
      float psum = 0.f;
#pragma unroll
      for (int i = 0; i < 16; ++i) {
        const float p = __expf(s[i] - mn);
        psum += p;
        const float4* vp = (const float4*)&Vt[j0 + i][half * 32];
#pragma unroll
        for (int d4 = 0; d4 < 8; ++d4) oa[d4] = fma4s(p, vp[d4], oa[d4]);
      }
      lsum += psum;
      m = mn;
    }
  }
  const float inv = 1.f / lsum;
  unsigned short* op = out + (size_t)(b * TT + tq) * DD + hh * 64 + half * 32;
#pragma unroll
  for (int d4 = 0; d4 < 8; ++d4) {
    ushort4 u;
    u.x = f2bf(oa[d4].x * inv); u.y = f2bf(oa[d4].y * inv);
    u.z = f2bf(oa[d4].z * inv); u.w = f2bf(oa[d4].w * inv);
    *(ushort4*)(op + d4 * 4) = u;
  }
}

// ---------------------------------------------------------------- host
extern "C" void kernel_launch(void* const* d_in, const int* in_sizes, int n_in,
                              void* d_out, int out_size, void* d_ws, size_t ws_size,
                              hipStream_t stream) {
  (void)in_sizes; (void)n_in; (void)out_size; (void)ws_size;
  const int* ids = (const int*)d_in[0];
  const float* wte = (const float*)d_in[1];
  const float* wpe = (const float*)d_in[2];
  const float* ln1w = (const float*)d_in[3];
  const float* ln1b = (const float*)d_in[4];
  const float* attnw = (const float*)d_in[5];
  const float* attnb = (const float*)d_in[6];
  const float* attnla = (const float*)d_in[7];
  const float* attnlb = (const float*)d_in[8];
  const float* projw = (const float*)d_in[9];
  const float* projb = (const float*)d_in[10];
  const float* projla = (const float*)d_in[11];
  const float* projlb = (const float*)d_in[12];
  const float* ln2w = (const float*)d_in[13];
  const float* ln2b = (const float*)d_in[14];
  const float* fcw = (const float*)d_in[15];
  const float* fcb = (const float*)d_in[16];
  const float* fcla = (const float*)d_in[17];
  const float* fclb = (const float*)d_in[18];
  const float* mpw = (const float*)d_in[19];
  const float* mpb = (const float*)d_in[20];
  const float* mpla = (const float*)d_in[21];
  const float* mplb = (const float*)d_in[22];
  const float* lnfw = (const float*)d_in[23];
  const float* lnfb = (const float*)d_in[24];

  char* ws = (char*)d_ws;
  float* h = (float*)ws;                       ws += (size_t)MM * DD * 4;      // 8MB
  unsigned short* x = (unsigned short*)ws;     ws += (size_t)MM * DD * 2;      // 4MB
  float* hqkv = (float*)ws;                    ws += (size_t)MM * 3 * DD * 4;  // 24MB
  unsigned short* ho = (unsigned short*)ws;    ws += (size_t)MM * DD * 2;      // 4MB
  unsigned short* hm = (unsigned short*)ws;    ws += (size_t)MM * 4 * DD * 2;  // 16MB
  unsigned short* wqkv = (unsigned short*)ws;  ws += (size_t)3 * DD * DD * 2;
  unsigned short* wproj = (unsigned short*)ws; ws += (size_t)DD * DD * 2;
  unsigned short* wfc = (unsigned short*)ws;   ws += (size_t)4 * DD * DD * 2;
  unsigned short* wmp = (unsigned short*)ws;   ws += (size_t)DD * 4 * DD * 2;

  hipLaunchKernelGGL(embed_k, dim3(MM * DD / 256), dim3(256), 0, stream, ids, wte, wpe, h);

  for (int l = 0; l < NL; ++l) {
    const float* aw = attnw + (size_t)l * 3 * DD * DD;
    const float* ab = attnb + (size_t)l * 3 * DD;
    const float* pw = projw + (size_t)l * DD * DD;
    const float* pb = projb + (size_t)l * DD;
    const float* fw = fcw + (size_t)l * 4 * DD * DD;
    const float* fb = fcb + (size_t)l * 4 * DD;
    const float* mw = mpw + (size_t)l * DD * 4 * DD;
    const float* mb = mpb + (size_t)l * DD;

    // fold LoRA into bf16 weights
    hipLaunchKernelGGL(fusew_k, dim3(DD / 256, 3 * DD / 16), dim3(256), 0, stream,
                       aw, attnla + (size_t)l * RR * DD, attnlb + (size_t)l * 3 * DD * RR,
                       wqkv, 3 * DD, DD);
    hipLaunchKernelGGL(fusew_k, dim3(DD / 256, DD / 16), dim3(256), 0, stream,
                       pw, projla + (size_t)l * RR * DD, projlb + (size_t)l * DD * RR,
                       wproj, DD, DD);
    hipLaunchKernelGGL(fusew_k, dim3(DD / 256, 4 * DD / 16), dim3(256), 0, stream,
                       fw, fcla + (size_t)l * RR * DD, fclb + (size_t)l * 4 * DD * RR,
                       wfc, 4 * DD, DD);
    hipLaunchKernelGGL(fusew_k, dim3(4 * DD / 256, DD / 16), dim3(256), 0, stream,
                       mw, mpla + (size_t)l * RR * 4 * DD, mplb + (size_t)l * DD * RR,
                       wmp, DD, 4 * DD);

    // x = LN1(h)  [bf16]
    hipLaunchKernelGGL(ln_bf_k, dim3(MM), dim3(256), 0, stream, h,
                       ln1w + (size_t)l * DD, ln1b + (size_t)l * DD, x);
    // qkv = x @ wqkv^T + ab  [fp32]
    hipLaunchKernelGGL(gemm_bf16<0>, dim3(3 * DD / BN, MM / BM), dim3(256), 0, stream,
                       x, wqkv, ab, (const float*)nullptr, hqkv, (unsigned short*)nullptr,
                       MM, 3 * DD, DD);
    // o = attention(qkv)  [bf16]
    hipLaunchKernelGGL(attn2_k, dim3(TT / 64, NB * NH), dim3(128), 0, stream, hqkv, ho);
    // h = h + o @ wproj^T + pb
    hipLaunchKernelGGL(gemm_bf16<1>, dim3(DD / BN, MM / BM), dim3(256), 0, stream,
                       ho, wproj, pb, h, h, (unsigned short*)nullptr, MM, DD, DD);
    // x = LN2(h)
    hipLaunchKernelGGL(ln_bf_k, dim3(MM), dim3(256), 0, stream, h,
                       ln2w + (size_t)l * DD, ln2b + (size_t)l * DD, x);
    // m = gelu(x @ wfc^T + fb)  [bf16]
    hipLaunchKernelGGL(gemm_bf16<2>, dim3(4 * DD / BN, MM / BM), dim3(256), 0, stream,
                       x, wfc, fb, (const float*)nullptr, (float*)nullptr, hm,
                       MM, 4 * DD, DD);
    // h = h + m @ wmp^T + mb
    hipLaunchKernelGGL(gemm_bf16<1>, dim3(DD / BN, MM / BM), dim3(256), 0, stream,
                       hm, wmp, mb, h, h, (unsigned short*)nullptr, MM, DD, 4 * DD);
  }

  hipLaunchKernelGGL(ln_f_k, dim3(MM), dim3(256), 0, stream, h, lnfw, lnfb, (float*)d_out);
}

// Round 3
// 3009.154 us; speedup vs baseline: 9.7972x; 2.1383x over previous
//
#include <hip/hip_runtime.h>
#include <math.h>

#define TT 1024
#define DD 1024
#define NH 16
#define NB 2
#define NL 12
#define RR 32
#define MM (NB * TT)  // 2048

typedef __attribute__((ext_vector_type(8))) short bf16x8;
typedef __attribute__((ext_vector_type(4))) float f32x4;

__device__ __forceinline__ unsigned short f2bf(float f) {
  unsigned int u = __float_as_uint(f);
  u = (u + 0x7FFFu + ((u >> 16) & 1u)) >> 16;
  return (unsigned short)u;
}

typedef __attribute__((address_space(1))) void gvoid;
typedef __attribute__((address_space(3))) void lvoid;
__device__ __forceinline__ void gload_lds16(const void* g, void* l) {
  __builtin_amdgcn_global_load_lds((gvoid*)g, (lvoid*)l, 16, 0, 0);
}

// ---------------------------------------------------------------- embed
__global__ __launch_bounds__(256) void embed_k(const int* __restrict__ ids,
                                               const float* __restrict__ wte,
                                               const float* __restrict__ wpe,
                                               float* __restrict__ h) {
  const int i = blockIdx.x * 256 + threadIdx.x;
  const int row = i >> 10;
  const int d = i & 1023;
  const int t = row & (TT - 1);
  const int id = ids[row];
  h[i] = wte[(size_t)id * DD + d] + wpe[(size_t)t * DD + d];
}

// ---------------------------------------------------------------- layernorm (fp32 in, bf16 out)
__global__ __launch_bounds__(256) void ln_bf_k(const float* __restrict__ x,
                                               const float* __restrict__ w,
                                               const float* __restrict__ b,
                                               unsigned short* __restrict__ out) {
  const int row = blockIdx.x;
  const float* xr = x + (size_t)row * DD;
  const float4 v = *(const float4*)(xr + threadIdx.x * 4);
  float s = v.x + v.y + v.z + v.w;
  float ss = v.x * v.x + v.y * v.y + v.z * v.z + v.w * v.w;
#pragma unroll
  for (int off = 32; off > 0; off >>= 1) {
    s += __shfl_down(s, off);
    ss += __shfl_down(ss, off);
  }
  __shared__ float rs[4], rss[4];
  const int wid = threadIdx.x >> 6;
  if ((threadIdx.x & 63) == 0) { rs[wid] = s; rss[wid] = ss; }
  __syncthreads();
  s = rs[0] + rs[1] + rs[2] + rs[3];
  ss = rss[0] + rss[1] + rss[2] + rss[3];
  const float mean = s * (1.f / DD);
  const float var = ss * (1.f / DD) - mean * mean;
  const float rstd = rsqrtf(var + 1e-5f);
  const float4 wv = *(const float4*)(w + threadIdx.x * 4);
  const float4 bv = *(const float4*)(b + threadIdx.x * 4);
  ushort4 o;
  o.x = f2bf((v.x - mean) * rstd * wv.x + bv.x);
  o.y = f2bf((v.y - mean) * rstd * wv.y + bv.y);
  o.z = f2bf((v.z - mean) * rstd * wv.z + bv.z);
  o.w = f2bf((v.w - mean) * rstd * wv.w + bv.w);
  *(ushort4*)(out + (size_t)row * DD + threadIdx.x * 4) = o;
}

// final layernorm fp32 out
__global__ __launch_bounds__(256) void ln_f_k(const float* __restrict__ x,
                                              const float* __restrict__ w,
                                              const float* __restrict__ b,
                                              float* __restrict__ out) {
  const int row = blockIdx.x;
  const float* xr = x + (size_t)row * DD;
  const float4 v = *(const float4*)(xr + threadIdx.x * 4);
  float s = v.x + v.y + v.z + v.w;
  float ss = v.x * v.x + v.y * v.y + v.z * v.z + v.w * v.w;
#pragma unroll
  for (int off = 32; off > 0; off >>= 1) {
    s += __shfl_down(s, off);
    ss += __shfl_down(ss, off);
  }
  __shared__ float rs[4], rss[4];
  const int wid = threadIdx.x >> 6;
  if ((threadIdx.x & 63) == 0) { rs[wid] = s; rss[wid] = ss; }
  __syncthreads();
  s = rs[0] + rs[1] + rs[2] + rs[3];
  ss = rss[0] + rss[1] + rss[2] + rss[3];
  const float mean = s * (1.f / DD);
  const float var = ss * (1.f / DD) - mean * mean;
  const float rstd = rsqrtf(var + 1e-5f);
  const float4 wv = *(const float4*)(w + threadIdx.x * 4);
  const float4 bv = *(const float4*)(b + threadIdx.x * 4);
  float4 o;
  o.x = (v.x - mean) * rstd * wv.x + bv.x;
  o.y = (v.y - mean) * rstd * wv.y + bv.y;
  o.z = (v.z - mean) * rstd * wv.z + bv.z;
  o.w = (v.w - mean) * rstd * wv.w + bv.w;
  *(float4*)(out + (size_t)row * DD + threadIdx.x * 4) = o;
}

// ---------------------------------------------------------------- LoRA fold: out = bf16(W + 2*B@A)
__global__ __launch_bounds__(256) void fusew_k(const float* __restrict__ W,
                                               const float* __restrict__ Al,
                                               const float* __restrict__ Bl,
                                               unsigned short* __restrict__ out,
                                               int N, int K) {
  __shared__ float As[32][260];
  const int tid = threadIdx.x;
  const int k0 = blockIdx.x * 256;
  const int n0 = blockIdx.y * 16;
#pragma unroll
  for (int i = 0; i < 8; ++i) {
    const int f4 = tid + i * 256;
    const int r = f4 >> 6;
    const int c = (f4 & 63) * 4;
    *(float4*)&As[r][c] = *(const float4*)(Al + (size_t)r * K + k0 + c);
  }
  const int nl = tid >> 4;
  const int kl = (tid & 15) * 4;
  float br[32];
  {
    const float* bp = Bl + (size_t)(n0 + nl) * RR;
#pragma unroll
    for (int r = 0; r < 32; r += 4) {
      const float4 v = *(const float4*)(bp + r);
      br[r] = 2.f * v.x; br[r + 1] = 2.f * v.y;
      br[r + 2] = 2.f * v.z; br[r + 3] = 2.f * v.w;
    }
  }
  float acc[16];
  const float* wp = W + (size_t)(n0 + nl) * K + k0;
#pragma unroll
  for (int j = 0; j < 4; ++j) {
    const float4 v = *(const float4*)(wp + kl + j * 64);
    acc[j * 4 + 0] = v.x; acc[j * 4 + 1] = v.y;
    acc[j * 4 + 2] = v.z; acc[j * 4 + 3] = v.w;
  }
  __syncthreads();
#pragma unroll
  for (int r = 0; r < 32; ++r) {
    const float bb = br[r];
#pragma unroll
    for (int j = 0; j < 4; ++j) {
      const float4 a = *(const float4*)&As[r][kl + j * 64];
      acc[j * 4 + 0] = fmaf(bb, a.x, acc[j * 4 + 0]);
      acc[j * 4 + 1] = fmaf(bb, a.y, acc[j * 4 + 1]);
      acc[j * 4 + 2] = fmaf(bb, a.z, acc[j * 4 + 2]);
      acc[j * 4 + 3] = fmaf(bb, a.w, acc[j * 4 + 3]);
    }
  }
  unsigned short* op = out + (size_t)(n0 + nl) * K + k0;
#pragma unroll
  for (int j = 0; j < 4; ++j) {
    ushort4 u;
    u.x = f2bf(acc[j * 4 + 0]); u.y = f2bf(acc[j * 4 + 1]);
    u.z = f2bf(acc[j * 4 + 2]); u.w = f2bf(acc[j * 4 + 3]);
    *(ushort4*)(op + kl + j * 64) = u;
  }
}

// ---------------------------------------------------------------- bf16 MFMA GEMM
// MODE 1: fp32 out + res; MODE 2: gelu->bf16; MODE 3: qkv split (Q,K bf16 -> Cb stride 2048, V -> vt transposed)
#define BM 128
#define BN 128
#define BK 32
template <int MODE>
__global__ __launch_bounds__(256) void gemm_bf16(const unsigned short* __restrict__ A,
                                                 const unsigned short* __restrict__ Wt,
                                                 const float* __restrict__ bias,
                                                 const float* __restrict__ res,
                                                 float* __restrict__ Cf,
                                                 unsigned short* __restrict__ Cb,
                                                 unsigned short* __restrict__ vt,
                                                 int M, int N, int K) {
  __shared__ unsigned short As[BM * BK];
  __shared__ unsigned short Bs[BN * BK];
  const int tid = threadIdx.x;
  const int w = tid >> 6, l = tid & 63;
  const int bm = blockIdx.y * BM, bn = blockIdx.x * BN;
  const int wr = w >> 1, wc = w & 1;
  f32x4 acc[4][4] = {};
  const int srow = w * 32 + (l >> 2);
  const int scol = (l & 3) * 8;
  const unsigned short* ga = A + (size_t)(bm + srow) * K + scol;
  const unsigned short* gb = Wt + (size_t)(bn + srow) * K + scol;
  char* lA = (char*)As + w * 2048;
  char* lB = (char*)Bs + w * 2048;
  const int kb = (l >> 4) * 8;
  const int rA = wr * 64 + (l & 15);
  const int rB = wc * 64 + (l & 15);
  for (int k0 = 0; k0 < K; k0 += BK) {
    __syncthreads();
    gload_lds16(ga + k0, lA);
    gload_lds16(ga + k0 + (size_t)16 * K, lA + 1024);
    gload_lds16(gb + k0, lB);
    gload_lds16(gb + k0 + (size_t)16 * K, lB + 1024);
    __syncthreads();
    bf16x8 af[4], bf[4];
#pragma unroll
    for (int i = 0; i < 4; ++i) {
      af[i] = *(const bf16x8*)(As + (rA + i * 16) * BK + kb);
      bf[i] = *(const bf16x8*)(Bs + (rB + i * 16) * BK + kb);
    }
#pragma unroll
    for (int i = 0; i < 4; ++i)
#pragma unroll
      for (int j = 0; j < 4; ++j)
        acc[i][j] = __builtin_amdgcn_mfma_f32_16x16x32_bf16(af[i], bf[j], acc[i][j], 0, 0, 0);
  }
  const int cr = (l >> 4) * 4;
  const int cc = l & 15;
#pragma unroll
  for (int i = 0; i < 4; ++i) {
    const int gr0 = bm + wr * 64 + i * 16 + cr;
#pragma unroll
    for (int j = 0; j < 4; ++j) {
      const int gc = bn + wc * 64 + j * 16 + cc;
      const float bv = bias[gc];
      if (MODE == 3) {
        if (gc < 2048) {
#pragma unroll
          for (int r = 0; r < 4; ++r)
            Cb[(size_t)(gr0 + r) * 2048 + gc] = f2bf(acc[i][j][r] + bv);
        } else {
          const int hv = gc - 2048;
          const int b_ = gr0 >> 10, t0 = gr0 & 1023;
          ushort4 u;
          u.x = f2bf(acc[i][j][0] + bv); u.y = f2bf(acc[i][j][1] + bv);
          u.z = f2bf(acc[i][j][2] + bv); u.w = f2bf(acc[i][j][3] + bv);
          *(ushort4*)(vt + ((size_t)(b_ * 1024 + hv)) * 1024 + t0) = u;
        }
      } else {
#pragma unroll
        for (int r = 0; r < 4; ++r) {
          float v = acc[i][j][r] + bv;
          const size_t idx = (size_t)(gr0 + r) * N + gc;
          if (MODE == 1) {
            Cf[idx] = v + res[idx];
          } else {  // MODE 2
            v = 0.5f * v * (1.f + erff(v * 0.70710678118654752f));
            Cb[idx] = f2bf(v);
          }
        }
      }
    }
  }
}

// ---------------------------------------------------------------- MFMA flash attention
// qk bf16 [B*T, 2048] (Q | K per head), vt bf16 [B*H, 64, T], out bf16 [B*T, 1024]
// block 256 thr (4 waves) per (q-tile 64, b*h). Wave w: q rows w*16..+16.
#define SM_SCALE_LOG2E 0.18033688011112042f  // log2(e)/8
__global__ __launch_bounds__(256) void attn3_k(const unsigned short* __restrict__ qk,
                                               const unsigned short* __restrict__ vt,
                                               unsigned short* __restrict__ out) {
  const int qt = blockIdx.x;   // 0..15
  const int bh = blockIdx.y;   // 0..31
  const int b = bh >> 4, hh = bh & 15;
  const int tid = threadIdx.x;
  const int w = tid >> 6, l = tid & 63;
  const int lg = l >> 4;   // 0..3
  const int lr = l & 15;   // 0..15

  __shared__ unsigned short Kt[2][64 * 64];
  __shared__ unsigned short Vb[2][64 * 64];
  __shared__ unsigned short Pb[4][16 * 64];

  // Q fragments (A-operand): row lr, k = ks*32 + lg*8
  bf16x8 qf[2];
  {
    const unsigned short* qp =
        qk + ((size_t)(b * TT + qt * 64 + w * 16 + lr)) * 2048 + hh * 64 + lg * 8;
    qf[0] = *(const bf16x8*)(qp);
    qf[1] = *(const bf16x8*)(qp + 32);
  }
  f32x4 oacc[4] = {};
  float mrow[4] = {-1e30f, -1e30f, -1e30f, -1e30f};
  float lrow[4] = {0.f, 0.f, 0.f, 0.f};

  // stage tile kt into buffer buf: K rows kv=0..63 (d 0..63), Vb rows d=0..63 (kv 0..63)
  // LDS linear; global source chunk pre-swizzled: src_chunk = dst_chunk ^ (row&7)
  auto stage = [&](int buf, int kt) {
#pragma unroll
    for (int oo = 0; oo < 2; ++oo) {
      const int o = w + oo * 4;                 // 8-row group
      const int row = o * 8 + (l >> 3);
      const int sc = ((l & 7) ^ (l >> 3)) * 8;  // pre-swizzled element offset
      const unsigned short* ks =
          qk + ((size_t)(b * TT + kt * 64 + row)) * 2048 + 1024 + hh * 64 + sc;
      gload_lds16(ks, (char*)&Kt[buf][0] + o * 1024);
      const unsigned short* vs =
          vt + ((size_t)(bh * 64 + row)) * 1024 + kt * 64 + sc;
      gload_lds16(vs, (char*)&Vb[buf][0] + o * 1024);
    }
  };

  stage(0, 0);
  int cur = 0;
  unsigned short* Pw = &Pb[w][0];
  const int qlocal = w * 16 + lg * 4;  // + r

  for (int kt = 0; kt <= qt; ++kt) {
    __syncthreads();  // drains vmcnt -> buf[cur] ready
    if (kt < qt) stage(cur ^ 1, kt + 1);
    const unsigned short* Kb_ = &Kt[cur][0];
    const unsigned short* Vb_ = &Vb[cur][0];
    const int effc = lr & 7;

    // S = Q K^T  (rows q, cols kv)
    f32x4 s[4];
#pragma unroll
    for (int j = 0; j < 4; ++j) {
      f32x4 sj = {};
#pragma unroll
      for (int ks = 0; ks < 2; ++ks) {
        const bf16x8 kf = *(const bf16x8*)((const char*)Kb_ + (j * 16 + lr) * 128 +
                                           (((ks * 4 + lg) ^ effc) * 16));
        sj = __builtin_amdgcn_mfma_f32_16x16x32_bf16(qf[ks], kf, sj, 0, 0, 0);
      }
      s[j] = sj;
    }

    // online softmax
    const bool last = (kt == qt);
    float tv[4][4];
#pragma unroll
    for (int j = 0; j < 4; ++j)
#pragma unroll
      for (int r = 0; r < 4; ++r) {
        float v = s[j][r] * SM_SCALE_LOG2E;
        if (last && (j * 16 + lr > qlocal + r)) v = -1e30f;
        tv[j][r] = v;
      }
    float corr[4];
#pragma unroll
    for (int r = 0; r < 4; ++r) {
      float mx = fmaxf(fmaxf(tv[0][r], tv[1][r]), fmaxf(tv[2][r], tv[3][r]));
      mx = fmaxf(mx, __shfl_xor(mx, 1));
      mx = fmaxf(mx, __shfl_xor(mx, 2));
      mx = fmaxf(mx, __shfl_xor(mx, 4));
      mx = fmaxf(mx, __shfl_xor(mx, 8));
      const float mn = fmaxf(mrow[r], mx);
      corr[r] = exp2f(mrow[r] - mn);
      mrow[r] = mn;
      lrow[r] *= corr[r];
    }
#pragma unroll
    for (int dt = 0; dt < 4; ++dt) {
      oacc[dt][0] *= corr[0]; oacc[dt][1] *= corr[1];
      oacc[dt][2] *= corr[2]; oacc[dt][3] *= corr[3];
    }
#pragma unroll
    for (int j = 0; j < 4; ++j)
#pragma unroll
      for (int r = 0; r < 4; ++r) {
        const float p = exp2f(tv[j][r] - mrow[r]);
        lrow[r] += p;
        const int q = lg * 4 + r;
        const int kv = j * 16 + lr;
        *(unsigned short*)((char*)Pw + q * 128 + ((kv * 2) ^ ((q & 7) << 4))) = f2bf(p);
      }
    asm volatile("s_waitcnt lgkmcnt(0)" ::: "memory");
    __builtin_amdgcn_sched_barrier(0);

    // O += P V   (A = P rows q, B = Vb rows d)
#pragma unroll
    for (int ks = 0; ks < 2; ++ks) {
      const bf16x8 pf = *(const bf16x8*)((const char*)Pw + lr * 128 +
                                         (((ks * 4 + lg) ^ effc) * 16));
#pragma unroll
      for (int dt = 0; dt < 4; ++dt) {
        const bf16x8 vf = *(const bf16x8*)((const char*)Vb_ + (dt * 16 + lr) * 128 +
                                           (((ks * 4 + lg) ^ effc) * 16));
        oacc[dt] = __builtin_amdgcn_mfma_f32_16x16x32_bf16(pf, vf, oacc[dt], 0, 0, 0);
      }
    }
    cur ^= 1;
  }

  // finalize: reduce lrow across 16-lane group, scale, store
#pragma unroll
  for (int r = 0; r < 4; ++r) {
    float lv = lrow[r];
    lv += __shfl_xor(lv, 1);
    lv += __shfl_xor(lv, 2);
    lv += __shfl_xor(lv, 4);
    lv += __shfl_xor(lv, 8);
    lrow[r] = 1.f / lv;
  }
  unsigned short* ob = out + ((size_t)(b * TT + qt * 64 + w * 16 + lg * 4)) * 1024 + hh * 64 + lr;
#pragma unroll
  for (int r = 0; r < 4; ++r)
#pragma unroll
    for (int dt = 0; dt < 4; ++dt)
      ob[(size_t)r * 1024 + dt * 16] = f2bf(oacc[dt][r] * lrow[r]);
}

// ---------------------------------------------------------------- host
extern "C" void kernel_launch(void* const* d_in, const int* in_sizes, int n_in,
                              void* d_out, int out_size, void* d_ws, size_t ws_size,
                              hipStream_t stream) {
  (void)in_sizes; (void)n_in; (void)out_size; (void)ws_size;
  const int* ids = (const int*)d_in[0];
  const float* wte = (const float*)d_in[1];
  const float* wpe = (const float*)d_in[2];
  const float* ln1w = (const float*)d_in[3];
  const float* ln1b = (const float*)d_in[4];
  const float* attnw = (const float*)d_in[5];
  const float* attnb = (const float*)d_in[6];
  const float* attnla = (const float*)d_in[7];
  const float* attnlb = (const float*)d_in[8];
  const float* projw = (const float*)d_in[9];
  const float* projb = (const float*)d_in[10];
  const float* projla = (const float*)d_in[11];
  const float* projlb = (const float*)d_in[12];
  const float* ln2w = (const float*)d_in[13];
  const float* ln2b = (const float*)d_in[14];
  const float* fcw = (const float*)d_in[15];
  const float* fcb = (const float*)d_in[16];
  const float* fcla = (const float*)d_in[17];
  const float* fclb = (const float*)d_in[18];
  const float* mpw = (const float*)d_in[19];
  const float* mpb = (const float*)d_in[20];
  const float* mpla = (const float*)d_in[21];
  const float* mplb = (const float*)d_in[22];
  const float* lnfw = (const float*)d_in[23];
  const float* lnfb = (const float*)d_in[24];

  char* ws = (char*)d_ws;
  float* h = (float*)ws;                       ws += (size_t)MM * DD * 4;      // 8MB
  unsigned short* x = (unsigned short*)ws;     ws += (size_t)MM * DD * 2;      // 4MB
  unsigned short* qkb = (unsigned short*)ws;   ws += (size_t)MM * 2 * DD * 2;  // 8MB
  unsigned short* vtb = (unsigned short*)ws;   ws += (size_t)MM * DD * 2;      // 4MB
  unsigned short* ho = (unsigned short*)ws;    ws += (size_t)MM * DD * 2;      // 4MB
  unsigned short* hm = (unsigned short*)ws;    ws += (size_t)MM * 4 * DD * 2;  // 16MB
  unsigned short* wqkv = (unsigned short*)ws;  ws += (size_t)3 * DD * DD * 2;
  unsigned short* wproj = (unsigned short*)ws; ws += (size_t)DD * DD * 2;
  unsigned short* wfc = (unsigned short*)ws;   ws += (size_t)4 * DD * DD * 2;
  unsigned short* wmp = (unsigned short*)ws;   ws += (size_t)DD * 4 * DD * 2;

  hipLaunchKernelGGL(embed_k, dim3(MM * DD / 256), dim3(256), 0, stream, ids, wte, wpe, h);

  for (int l = 0; l < NL; ++l) {
    const float* aw = attnw + (size_t)l * 3 * DD * DD;
    const float* ab = attnb + (size_t)l * 3 * DD;
    const float* pw = projw + (size_t)l * DD * DD;
    const float* pb = projb + (size_t)l * DD;
    const float* fw = fcw + (size_t)l * 4 * DD * DD;
    const float* fb = fcb + (size_t)l * 4 * DD;
    const float* mw = mpw + (size_t)l * DD * 4 * DD;
    const float* mb = mpb + (size_t)l * DD;

    hipLaunchKernelGGL(fusew_k, dim3(DD / 256, 3 * DD / 16), dim3(256), 0, stream,
                       aw, attnla + (size_t)l * RR * DD, attnlb + (size_t)l * 3 * DD * RR,
                       wqkv, 3 * DD, DD);
    hipLaunchKernelGGL(fusew_k, dim3(DD / 256, DD / 16), dim3(256), 0, stream,
                       pw, projla + (size_t)l * RR * DD, projlb + (size_t)l * DD * RR,
                       wproj, DD, DD);
    hipLaunchKernelGGL(fusew_k, dim3(DD / 256, 4 * DD / 16), dim3(256), 0, stream,
                       fw, fcla + (size_t)l * RR * DD, fclb + (size_t)l * 4 * DD * RR,
                       wfc, 4 * DD, DD);
    hipLaunchKernelGGL(fusew_k, dim3(4 * DD / 256, DD / 16), dim3(256), 0, stream,
                       mw, mpla + (size_t)l * RR * 4 * DD, mplb + (size_t)l * DD * RR,
                       wmp, DD, 4 * DD);

    // x = LN1(h)
    hipLaunchKernelGGL(ln_bf_k, dim3(MM), dim3(256), 0, stream, h,
                       ln1w + (size_t)l * DD, ln1b + (size_t)l * DD, x);
    // qkv = x @ wqkv^T + ab -> qkb (Q,K) + vtb (V transposed)
    hipLaunchKernelGGL(gemm_bf16<3>, dim3(3 * DD / BN, MM / BM), dim3(256), 0, stream,
                       x, wqkv, ab, (const float*)nullptr, (float*)nullptr, qkb, vtb,
                       MM, 3 * DD, DD);
    // o = attention
    hipLaunchKernelGGL(attn3_k, dim3(TT / 64, NB * NH), dim3(256), 0, stream, qkb, vtb, ho);
    // h = h + o @ wproj^T + pb
    hipLaunchKernelGGL(gemm_bf16<1>, dim3(DD / BN, MM / BM), dim3(256), 0, stream,
                       ho, wproj, pb, h, h, (unsigned short*)nullptr,
                       (unsigned short*)nullptr, MM, DD, DD);
    // x = LN2(h)
    hipLaunchKernelGGL(ln_bf_k, dim3(MM), dim3(256), 0, stream, h,
                       ln2w + (size_t)l * DD, ln2b + (size_t)l * DD, x);
    // m = gelu(x @ wfc^T + fb)
    hipLaunchKernelGGL(gemm_bf16<2>, dim3(4 * DD / BN, MM / BM), dim3(256), 0, stream,
                       x, wfc, fb, (const float*)nullptr, (float*)nullptr, hm,
                       (unsigned short*)nullptr, MM, 4 * DD, DD);
    // h = h + m @ wmp^T + mb
    hipLaunchKernelGGL(gemm_bf16<1>, dim3(DD / BN, MM / BM), dim3(256), 0, stream,
                       hm, wmp, mb, h, h, (unsigned short*)nullptr,
                       (unsigned short*)nullptr, MM, DD, 4 * DD);
  }

  hipLaunchKernelGGL(ln_f_k, dim3(MM), dim3(256), 0, stream, h, lnfw, lnfb, (float*)d_out);
}

// Round 4
// 2953.089 us; speedup vs baseline: 9.9832x; 1.0190x over previous
//
#include <hip/hip_runtime.h>
#include <math.h>

#define TT 1024
#define DD 1024
#define NH 16
#define NB 2
#define NL 12
#define RR 32
#define MM (NB * TT)  // 2048

typedef __attribute__((ext_vector_type(8))) short bf16x8;
typedef __attribute__((ext_vector_type(4))) float f32x4;

__device__ __forceinline__ unsigned short f2bf(float f) {
  unsigned int u = __float_as_uint(f);
  u = (u + 0x7FFFu + ((u >> 16) & 1u)) >> 16;
  return (unsigned short)u;
}

typedef __attribute__((address_space(1))) void gvoid;
typedef __attribute__((address_space(3))) void lvoid;
__device__ __forceinline__ void gload_lds16(const void* g, void* l) {
  __builtin_amdgcn_global_load_lds((gvoid*)g, (lvoid*)l, 16, 0, 0);
}

// ---------------------------------------------------------------- embed
__global__ __launch_bounds__(256) void embed_k(const int* __restrict__ ids,
                                               const float* __restrict__ wte,
                                               const float* __restrict__ wpe,
                                               float* __restrict__ h) {
  const int i = blockIdx.x * 256 + threadIdx.x;
  const int row = i >> 10;
  const int d = i & 1023;
  const int t = row & (TT - 1);
  const int id = ids[row];
  h[i] = wte[(size_t)id * DD + d] + wpe[(size_t)t * DD + d];
}

// ---------------------------------------------------------------- layernorm (fp32 in, bf16 out)
__global__ __launch_bounds__(256) void ln_bf_k(const float* __restrict__ x,
                                               const float* __restrict__ w,
                                               const float* __restrict__ b,
                                               unsigned short* __restrict__ out) {
  const int row = blockIdx.x;
  const float* xr = x + (size_t)row * DD;
  const float4 v = *(const float4*)(xr + threadIdx.x * 4);
  float s = v.x + v.y + v.z + v.w;
  float ss = v.x * v.x + v.y * v.y + v.z * v.z + v.w * v.w;
#pragma unroll
  for (int off = 32; off > 0; off >>= 1) {
    s += __shfl_down(s, off);
    ss += __shfl_down(ss, off);
  }
  __shared__ float rs[4], rss[4];
  const int wid = threadIdx.x >> 6;
  if ((threadIdx.x & 63) == 0) { rs[wid] = s; rss[wid] = ss; }
  __syncthreads();
  s = rs[0] + rs[1] + rs[2] + rs[3];
  ss = rss[0] + rss[1] + rss[2] + rss[3];
  const float mean = s * (1.f / DD);
  const float var = ss * (1.f / DD) - mean * mean;
  const float rstd = rsqrtf(var + 1e-5f);
  const float4 wv = *(const float4*)(w + threadIdx.x * 4);
  const float4 bv = *(const float4*)(b + threadIdx.x * 4);
  ushort4 o;
  o.x = f2bf((v.x - mean) * rstd * wv.x + bv.x);
  o.y = f2bf((v.y - mean) * rstd * wv.y + bv.y);
  o.z = f2bf((v.z - mean) * rstd * wv.z + bv.z);
  o.w = f2bf((v.w - mean) * rstd * wv.w + bv.w);
  *(ushort4*)(out + (size_t)row * DD + threadIdx.x * 4) = o;
}

// final layernorm fp32 out
__global__ __launch_bounds__(256) void ln_f_k(const float* __restrict__ x,
                                              const float* __restrict__ w,
                                              const float* __restrict__ b,
                                              float* __restrict__ out) {
  const int row = blockIdx.x;
  const float* xr = x + (size_t)row * DD;
  const float4 v = *(const float4*)(xr + threadIdx.x * 4);
  float s = v.x + v.y + v.z + v.w;
  float ss = v.x * v.x + v.y * v.y + v.z * v.z + v.w * v.w;
#pragma unroll
  for (int off = 32; off > 0; off >>= 1) {
    s += __shfl_down(s, off);
    ss += __shfl_down(ss, off);
  }
  __shared__ float rs[4], rss[4];
  const int wid = threadIdx.x >> 6;
  if ((threadIdx.x & 63) == 0) { rs[wid] = s; rss[wid] = ss; }
  __syncthreads();
  s = rs[0] + rs[1] + rs[2] + rs[3];
  ss = rss[0] + rss[1] + rss[2] + rss[3];
  const float mean = s * (1.f / DD);
  const float var = ss * (1.f / DD) - mean * mean;
  const float rstd = rsqrtf(var + 1e-5f);
  const float4 wv = *(const float4*)(w + threadIdx.x * 4);
  const float4 bv = *(const float4*)(b + threadIdx.x * 4);
  float4 o;
  o.x = (v.x - mean) * rstd * wv.x + bv.x;
  o.y = (v.y - mean) * rstd * wv.y + bv.y;
  o.z = (v.z - mean) * rstd * wv.z + bv.z;
  o.w = (v.w - mean) * rstd * wv.w + bv.w;
  *(float4*)(out + (size_t)row * DD + threadIdx.x * 4) = o;
}

// ---------------------------------------------------------------- LoRA fold, all layers in ONE launch
// per layer 3072 blocks: [0,768) qkv(K=1024), [768,1024) proj(K=1024),
// [1024,2048) fc(K=1024), [2048,3072) mp(K=4096). tile = 16 n x 256 k.
__global__ __launch_bounds__(256) void fusew_all_k(
    const float* __restrict__ aw, const float* __restrict__ ala, const float* __restrict__ alb,
    const float* __restrict__ pw, const float* __restrict__ pla, const float* __restrict__ plb,
    const float* __restrict__ fw, const float* __restrict__ fla, const float* __restrict__ flb,
    const float* __restrict__ mw, const float* __restrict__ mla, const float* __restrict__ mlb,
    unsigned short* __restrict__ oq, unsigned short* __restrict__ op_,
    unsigned short* __restrict__ of, unsigned short* __restrict__ om) {
  const int g = blockIdx.x;
  const int layer = g / 3072;
  const int lid = g - layer * 3072;
  const float *W, *Al, *Bl;
  unsigned short* out;
  int K, k0, n0;
  if (lid < 768) {
    W = aw + (size_t)layer * 3 * DD * DD;
    Al = ala + (size_t)layer * RR * DD;
    Bl = alb + (size_t)layer * 3 * DD * RR;
    out = oq + (size_t)layer * 3 * DD * DD;
    K = DD; k0 = (lid & 3) * 256; n0 = (lid >> 2) * 16;
  } else if (lid < 1024) {
    const int t = lid - 768;
    W = pw + (size_t)layer * DD * DD;
    Al = pla + (size_t)layer * RR * DD;
    Bl = plb + (size_t)layer * DD * RR;
    out = op_ + (size_t)layer * DD * DD;
    K = DD; k0 = (t & 3) * 256; n0 = (t >> 2) * 16;
  } else if (lid < 2048) {
    const int t = lid - 1024;
    W = fw + (size_t)layer * 4 * DD * DD;
    Al = fla + (size_t)layer * RR * DD;
    Bl = flb + (size_t)layer * 4 * DD * RR;
    out = of + (size_t)layer * 4 * DD * DD;
    K = DD; k0 = (t & 3) * 256; n0 = (t >> 2) * 16;
  } else {
    const int t = lid - 2048;
    W = mw + (size_t)layer * DD * 4 * DD;
    Al = mla + (size_t)layer * RR * 4 * DD;
    Bl = mlb + (size_t)layer * DD * RR;
    out = om + (size_t)layer * DD * 4 * DD;
    K = 4 * DD; k0 = (t & 15) * 256; n0 = (t >> 4) * 16;
  }
  __shared__ float As[32][260];
  const int tid = threadIdx.x;
#pragma unroll
  for (int i = 0; i < 8; ++i) {
    const int f4 = tid + i * 256;
    const int r = f4 >> 6;
    const int c = (f4 & 63) * 4;
    *(float4*)&As[r][c] = *(const float4*)(Al + (size_t)r * K + k0 + c);
  }
  const int nl = tid >> 4;
  const int kl = (tid & 15) * 4;
  float br[32];
  {
    const float* bp = Bl + (size_t)(n0 + nl) * RR;
#pragma unroll
    for (int r = 0; r < 32; r += 4) {
      const float4 v = *(const float4*)(bp + r);
      br[r] = 2.f * v.x; br[r + 1] = 2.f * v.y;
      br[r + 2] = 2.f * v.z; br[r + 3] = 2.f * v.w;
    }
  }
  float acc[16];
  const float* wp = W + (size_t)(n0 + nl) * K + k0;
#pragma unroll
  for (int j = 0; j < 4; ++j) {
    const float4 v = *(const float4*)(wp + kl + j * 64);
    acc[j * 4 + 0] = v.x; acc[j * 4 + 1] = v.y;
    acc[j * 4 + 2] = v.z; acc[j * 4 + 3] = v.w;
  }
  __syncthreads();
#pragma unroll
  for (int r = 0; r < 32; ++r) {
    const float bb = br[r];
#pragma unroll
    for (int j = 0; j < 4; ++j) {
      const float4 a = *(const float4*)&As[r][kl + j * 64];
      acc[j * 4 + 0] = fmaf(bb, a.x, acc[j * 4 + 0]);
      acc[j * 4 + 1] = fmaf(bb, a.y, acc[j * 4 + 1]);
      acc[j * 4 + 2] = fmaf(bb, a.z, acc[j * 4 + 2]);
      acc[j * 4 + 3] = fmaf(bb, a.w, acc[j * 4 + 3]);
    }
  }
  unsigned short* opp = out + (size_t)(n0 + nl) * K + k0;
#pragma unroll
  for (int j = 0; j < 4; ++j) {
    ushort4 u;
    u.x = f2bf(acc[j * 4 + 0]); u.y = f2bf(acc[j * 4 + 1]);
    u.z = f2bf(acc[j * 4 + 2]); u.w = f2bf(acc[j * 4 + 3]);
    *(ushort4*)(opp + kl + j * 64) = u;
  }
}

// ---------------------------------------------------------------- bf16 MFMA GEMM (128x128)
// MODE 1: fp32 out + res; MODE 2: gelu->bf16; MODE 3: qkv split
#define BM 128
#define BN 128
#define BK 32
template <int MODE>
__global__ __launch_bounds__(256) void gemm_bf16(const unsigned short* __restrict__ A,
                                                 const unsigned short* __restrict__ Wt,
                                                 const float* __restrict__ bias,
                                                 const float* __restrict__ res,
                                                 float* __restrict__ Cf,
                                                 unsigned short* __restrict__ Cb,
                                                 unsigned short* __restrict__ vt,
                                                 int M, int N, int K) {
  __shared__ unsigned short As[BM * BK];
  __shared__ unsigned short Bs[BN * BK];
  const int tid = threadIdx.x;
  const int w = tid >> 6, l = tid & 63;
  const int bm = blockIdx.y * BM, bn = blockIdx.x * BN;
  const int wr = w >> 1, wc = w & 1;
  f32x4 acc[4][4] = {};
  const int srow = w * 32 + (l >> 2);
  const int scol = (l & 3) * 8;
  const unsigned short* ga = A + (size_t)(bm + srow) * K + scol;
  const unsigned short* gb = Wt + (size_t)(bn + srow) * K + scol;
  char* lA = (char*)As + w * 2048;
  char* lB = (char*)Bs + w * 2048;
  const int kb = (l >> 4) * 8;
  const int rA = wr * 64 + (l & 15);
  const int rB = wc * 64 + (l & 15);
  for (int k0 = 0; k0 < K; k0 += BK) {
    __syncthreads();
    gload_lds16(ga + k0, lA);
    gload_lds16(ga + k0 + (size_t)16 * K, lA + 1024);
    gload_lds16(gb + k0, lB);
    gload_lds16(gb + k0 + (size_t)16 * K, lB + 1024);
    __syncthreads();
    bf16x8 af[4], bf[4];
#pragma unroll
    for (int i = 0; i < 4; ++i) {
      af[i] = *(const bf16x8*)(As + (rA + i * 16) * BK + kb);
      bf[i] = *(const bf16x8*)(Bs + (rB + i * 16) * BK + kb);
    }
#pragma unroll
    for (int i = 0; i < 4; ++i)
#pragma unroll
      for (int j = 0; j < 4; ++j)
        acc[i][j] = __builtin_amdgcn_mfma_f32_16x16x32_bf16(af[i], bf[j], acc[i][j], 0, 0, 0);
  }
  const int cr = (l >> 4) * 4;
  const int cc = l & 15;
#pragma unroll
  for (int i = 0; i < 4; ++i) {
    const int gr0 = bm + wr * 64 + i * 16 + cr;
#pragma unroll
    for (int j = 0; j < 4; ++j) {
      const int gc = bn + wc * 64 + j * 16 + cc;
      const float bv = bias[gc];
      if (MODE == 3) {
        if (gc < 2048) {
#pragma unroll
          for (int r = 0; r < 4; ++r)
            Cb[(size_t)(gr0 + r) * 2048 + gc] = f2bf(acc[i][j][r] + bv);
        } else {
          const int hv = gc - 2048;
          const int b_ = gr0 >> 10, t0 = gr0 & 1023;
          ushort4 u;
          u.x = f2bf(acc[i][j][0] + bv); u.y = f2bf(acc[i][j][1] + bv);
          u.z = f2bf(acc[i][j][2] + bv); u.w = f2bf(acc[i][j][3] + bv);
          *(ushort4*)(vt + ((size_t)(b_ * 1024 + hv)) * 1024 + t0) = u;
        }
      } else {
#pragma unroll
        for (int r = 0; r < 4; ++r) {
          float v = acc[i][j][r] + bv;
          const size_t idx = (size_t)(gr0 + r) * N + gc;
          if (MODE == 1) {
            Cf[idx] = v + res[idx];
          } else {  // MODE 2
            v = 0.5f * v * (1.f + erff(v * 0.70710678118654752f));
            Cb[idx] = f2bf(v);
          }
        }
      }
    }
  }
}

// ---------------------------------------------------------------- bf16 MFMA GEMM (128x64, for small-N GEMMs)
// MODE 1 epilogue only: Cf = acc + bias + res. grid (N/64, M/128).
__global__ __launch_bounds__(256) void gemm_n64(const unsigned short* __restrict__ A,
                                                const unsigned short* __restrict__ Wt,
                                                const float* __restrict__ bias,
                                                const float* __restrict__ res,
                                                float* __restrict__ Cf,
                                                int M, int N, int K) {
  __shared__ unsigned short As[128 * BK];
  __shared__ unsigned short Bs[64 * BK];
  const int tid = threadIdx.x;
  const int w = tid >> 6, l = tid & 63;
  const int bm = blockIdx.y * 128, bn = blockIdx.x * 64;
  f32x4 acc[2][4] = {};
  const int srowA = w * 32 + (l >> 2);
  const int srowB = w * 16 + (l >> 2);
  const int scol = (l & 3) * 8;
  const unsigned short* ga = A + (size_t)(bm + srowA) * K + scol;
  const unsigned short* gb = Wt + (size_t)(bn + srowB) * K + scol;
  char* lA = (char*)As + w * 2048;
  char* lB = (char*)Bs + w * 1024;
  const int kb = (l >> 4) * 8;
  const int lr = l & 15;
  for (int k0 = 0; k0 < K; k0 += BK) {
    __syncthreads();
    gload_lds16(ga + k0, lA);
    gload_lds16(ga + k0 + (size_t)16 * K, lA + 1024);
    gload_lds16(gb + k0, lB);
    __syncthreads();
    bf16x8 af[2], bf[4];
#pragma unroll
    for (int i = 0; i < 2; ++i)
      af[i] = *(const bf16x8*)(As + (w * 32 + i * 16 + lr) * BK + kb);
#pragma unroll
    for (int j = 0; j < 4; ++j)
      bf[j] = *(const bf16x8*)(Bs + (j * 16 + lr) * BK + kb);
#pragma unroll
    for (int i = 0; i < 2; ++i)
#pragma unroll
      for (int j = 0; j < 4; ++j)
        acc[i][j] = __builtin_amdgcn_mfma_f32_16x16x32_bf16(af[i], bf[j], acc[i][j], 0, 0, 0);
  }
  const int cr = (l >> 4) * 4;
  const int cc = l & 15;
#pragma unroll
  for (int i = 0; i < 2; ++i) {
    const int gr0 = bm + w * 32 + i * 16 + cr;
#pragma unroll
    for (int j = 0; j < 4; ++j) {
      const int gc = bn + j * 16 + cc;
      const float bv = bias[gc];
#pragma unroll
      for (int r = 0; r < 4; ++r) {
        const size_t idx = (size_t)(gr0 + r) * N + gc;
        Cf[idx] = acc[i][j][r] + bv + res[idx];
      }
    }
  }
}

// ---------------------------------------------------------------- MFMA flash attention
// qk bf16 [B*T, 2048] (Q | K per head), vt bf16 [B*H, 64, T], out bf16 [B*T, 1024]
#define SM_SCALE_LOG2E 0.18033688011112042f  // log2(e)/8
__global__ __launch_bounds__(256) void attn3_k(const unsigned short* __restrict__ qk,
                                               const unsigned short* __restrict__ vt,
                                               unsigned short* __restrict__ out) {
  const int qt = blockIdx.x;
  const int bh = blockIdx.y;
  const int b = bh >> 4, hh = bh & 15;
  const int tid = threadIdx.x;
  const int w = tid >> 6, l = tid & 63;
  const int lg = l >> 4;
  const int lr = l & 15;

  __shared__ unsigned short Kt[2][64 * 64];
  __shared__ unsigned short Vb[2][64 * 64];
  __shared__ unsigned short Pb[4][16 * 64];

  bf16x8 qf[2];
  {
    const unsigned short* qp =
        qk + ((size_t)(b * TT + qt * 64 + w * 16 + lr)) * 2048 + hh * 64 + lg * 8;
    qf[0] = *(const bf16x8*)(qp);
    qf[1] = *(const bf16x8*)(qp + 32);
  }
  f32x4 oacc[4] = {};
  float mrow[4] = {-1e30f, -1e30f, -1e30f, -1e30f};
  float lrow[4] = {0.f, 0.f, 0.f, 0.f};

  auto stage = [&](int buf, int kt) {
#pragma unroll
    for (int oo = 0; oo < 2; ++oo) {
      const int o = w + oo * 4;
      const int row = o * 8 + (l >> 3);
      const int sc = ((l & 7) ^ (l >> 3)) * 8;
      const unsigned short* ks =
          qk + ((size_t)(b * TT + kt * 64 + row)) * 2048 + 1024 + hh * 64 + sc;
      gload_lds16(ks, (char*)&Kt[buf][0] + o * 1024);
      const unsigned short* vs =
          vt + ((size_t)(bh * 64 + row)) * 1024 + kt * 64 + sc;
      gload_lds16(vs, (char*)&Vb[buf][0] + o * 1024);
    }
  };

  stage(0, 0);
  int cur = 0;
  unsigned short* Pw = &Pb[w][0];
  const int qlocal = w * 16 + lg * 4;

  for (int kt = 0; kt <= qt; ++kt) {
    __syncthreads();
    if (kt < qt) stage(cur ^ 1, kt + 1);
    const unsigned short* Kb_ = &Kt[cur][0];
    const unsigned short* Vb_ = &Vb[cur][0];
    const int effc = lr & 7;

    f32x4 s[4];
#pragma unroll
    for (int j = 0; j < 4; ++j) {
      f32x4 sj = {};
#pragma unroll
      for (int ks = 0; ks < 2; ++ks) {
        const bf16x8 kf = *(const bf16x8*)((const char*)Kb_ + (j * 16 + lr) * 128 +
                                           (((ks * 4 + lg) ^ effc) * 16));
        sj = __builtin_amdgcn_mfma_f32_16x16x32_bf16(qf[ks], kf, sj, 0, 0, 0);
      }
      s[j] = sj;
    }

    const bool last = (kt == qt);
    float tv[4][4];
#pragma unroll
    for (int j = 0; j < 4; ++j)
#pragma unroll
      for (int r = 0; r < 4; ++r) {
        float v = s[j][r] * SM_SCALE_LOG2E;
        if (last && (j * 16 + lr > qlocal + r)) v = -1e30f;
        tv[j][r] = v;
      }
    float corr[4];
#pragma unroll
    for (int r = 0; r < 4; ++r) {
      float mx = fmaxf(fmaxf(tv[0][r], tv[1][r]), fmaxf(tv[2][r], tv[3][r]));
      mx = fmaxf(mx, __shfl_xor(mx, 1));
      mx = fmaxf(mx, __shfl_xor(mx, 2));
      mx = fmaxf(mx, __shfl_xor(mx, 4));
      mx = fmaxf(mx, __shfl_xor(mx, 8));
      const float mn = fmaxf(mrow[r], mx);
      corr[r] = exp2f(mrow[r] - mn);
      mrow[r] = mn;
      lrow[r] *= corr[r];
    }
#pragma unroll
    for (int dt = 0; dt < 4; ++dt) {
      oacc[dt][0] *= corr[0]; oacc[dt][1] *= corr[1];
      oacc[dt][2] *= corr[2]; oacc[dt][3] *= corr[3];
    }
#pragma unroll
    for (int j = 0; j < 4; ++j)
#pragma unroll
      for (int r = 0; r < 4; ++r) {
        const float p = exp2f(tv[j][r] - mrow[r]);
        lrow[r] += p;
        const int q = lg * 4 + r;
        const int kv = j * 16 + lr;
        *(unsigned short*)((char*)Pw + q * 128 + ((kv * 2) ^ ((q & 7) << 4))) = f2bf(p);
      }
    asm volatile("s_waitcnt lgkmcnt(0)" ::: "memory");
    __builtin_amdgcn_sched_barrier(0);

#pragma unroll
    for (int ks = 0; ks < 2; ++ks) {
      const bf16x8 pf = *(const bf16x8*)((const char*)Pw + lr * 128 +
                                         (((ks * 4 + lg) ^ effc) * 16));
#pragma unroll
      for (int dt = 0; dt < 4; ++dt) {
        const bf16x8 vf = *(const bf16x8*)((const char*)Vb_ + (dt * 16 + lr) * 128 +
                                           (((ks * 4 + lg) ^ effc) * 16));
        oacc[dt] = __builtin_amdgcn_mfma_f32_16x16x32_bf16(pf, vf, oacc[dt], 0, 0, 0);
      }
    }
    cur ^= 1;
  }

#pragma unroll
  for (int r = 0; r < 4; ++r) {
    float lv = lrow[r];
    lv += __shfl_xor(lv, 1);
    lv += __shfl_xor(lv, 2);
    lv += __shfl_xor(lv, 4);
    lv += __shfl_xor(lv, 8);
    lrow[r] = 1.f / lv;
  }
  unsigned short* ob = out + ((size_t)(b * TT + qt * 64 + w * 16 + lg * 4)) * 1024 + hh * 64 + lr;
#pragma unroll
  for (int r = 0; r < 4; ++r)
#pragma unroll
    for (int dt = 0; dt < 4; ++dt)
      ob[(size_t)r * 1024 + dt * 16] = f2bf(oacc[dt][r] * lrow[r]);
}

// ---------------------------------------------------------------- host
extern "C" void kernel_launch(void* const* d_in, const int* in_sizes, int n_in,
                              void* d_out, int out_size, void* d_ws, size_t ws_size,
                              hipStream_t stream) {
  (void)in_sizes; (void)n_in; (void)out_size; (void)ws_size;
  const int* ids = (const int*)d_in[0];
  const float* wte = (const float*)d_in[1];
  const float* wpe = (const float*)d_in[2];
  const float* ln1w = (const float*)d_in[3];
  const float* ln1b = (const float*)d_in[4];
  const float* attnw = (const float*)d_in[5];
  const float* attnb = (const float*)d_in[6];
  const float* attnla = (const float*)d_in[7];
  const float* attnlb = (const float*)d_in[8];
  const float* projw = (const float*)d_in[9];
  const float* projb = (const float*)d_in[10];
  const float* projla = (const float*)d_in[11];
  const float* projlb = (const float*)d_in[12];
  const float* ln2w = (const float*)d_in[13];
  const float* ln2b = (const float*)d_in[14];
  const float* fcw = (const float*)d_in[15];
  const float* fcb = (const float*)d_in[16];
  const float* fcla = (const float*)d_in[17];
  const float* fclb = (const float*)d_in[18];
  const float* mpw = (const float*)d_in[19];
  const float* mpb = (const float*)d_in[20];
  const float* mpla = (const float*)d_in[21];
  const float* mplb = (const float*)d_in[22];
  const float* lnfw = (const float*)d_in[23];
  const float* lnfb = (const float*)d_in[24];

  char* ws = (char*)d_ws;
  float* h = (float*)ws;                        ws += (size_t)MM * DD * 4;       // 8MB
  unsigned short* x = (unsigned short*)ws;      ws += (size_t)MM * DD * 2;       // 4MB
  unsigned short* qkb = (unsigned short*)ws;    ws += (size_t)MM * 2 * DD * 2;   // 8MB
  unsigned short* vtb = (unsigned short*)ws;    ws += (size_t)MM * DD * 2;       // 4MB
  unsigned short* ho = (unsigned short*)ws;     ws += (size_t)MM * DD * 2;       // 4MB
  unsigned short* hm = (unsigned short*)ws;     ws += (size_t)MM * 4 * DD * 2;   // 16MB
  unsigned short* wqkvA = (unsigned short*)ws;  ws += (size_t)NL * 3 * DD * DD * 2;  // 72MB
  unsigned short* wprojA = (unsigned short*)ws; ws += (size_t)NL * DD * DD * 2;      // 24MB
  unsigned short* wfcA = (unsigned short*)ws;   ws += (size_t)NL * 4 * DD * DD * 2;  // 96MB
  unsigned short* wmpA = (unsigned short*)ws;   ws += (size_t)NL * DD * 4 * DD * 2;  // 96MB

  hipLaunchKernelGGL(embed_k, dim3(MM * DD / 256), dim3(256), 0, stream, ids, wte, wpe, h);

  // fold all LoRA weights for all layers in one launch
  hipLaunchKernelGGL(fusew_all_k, dim3(NL * 3072), dim3(256), 0, stream,
                     attnw, attnla, attnlb, projw, projla, projlb,
                     fcw, fcla, fclb, mpw, mpla, mplb,
                     wqkvA, wprojA, wfcA, wmpA);

  for (int l = 0; l < NL; ++l) {
    const float* ab = attnb + (size_t)l * 3 * DD;
    const float* pb = projb + (size_t)l * DD;
    const float* fb = fcb + (size_t)l * 4 * DD;
    const float* mb = mpb + (size_t)l * DD;
    const unsigned short* wqkv = wqkvA + (size_t)l * 3 * DD * DD;
    const unsigned short* wproj = wprojA + (size_t)l * DD * DD;
    const unsigned short* wfc = wfcA + (size_t)l * 4 * DD * DD;
    const unsigned short* wmp = wmpA + (size_t)l * DD * 4 * DD;

    // x = LN1(h)
    hipLaunchKernelGGL(ln_bf_k, dim3(MM), dim3(256), 0, stream, h,
                       ln1w + (size_t)l * DD, ln1b + (size_t)l * DD, x);
    // qkv = x @ wqkv^T + ab -> qkb (Q,K) + vtb (V transposed)
    hipLaunchKernelGGL(gemm_bf16<3>, dim3(3 * DD / BN, MM / BM), dim3(256), 0, stream,
                       x, wqkv, ab, (const float*)nullptr, (float*)nullptr, qkb, vtb,
                       MM, 3 * DD, DD);
    // o = attention
    hipLaunchKernelGGL(attn3_k, dim3(TT / 64, NB * NH), dim3(256), 0, stream, qkb, vtb, ho);
    // h = h + o @ wproj^T + pb
    hipLaunchKernelGGL(gemm_n64, dim3(DD / 64, MM / 128), dim3(256), 0, stream,
                       ho, wproj, pb, h, h, MM, DD, DD);
    // x = LN2(h)
    hipLaunchKernelGGL(ln_bf_k, dim3(MM), dim3(256), 0, stream, h,
                       ln2w + (size_t)l * DD, ln2b + (size_t)l * DD, x);
    // m = gelu(x @ wfc^T + fb)
    hipLaunchKernelGGL(gemm_bf16<2>, dim3(4 * DD / BN, MM / BM), dim3(256), 0, stream,
                       x, wfc, fb, (const float*)nullptr, (float*)nullptr, hm,
                       (unsigned short*)nullptr, MM, 4 * DD, DD);
    // h = h + m @ wmp^T + mb
    hipLaunchKernelGGL(gemm_n64, dim3(DD / 64, MM / 128), dim3(256), 0, stream,
                       hm, wmp, mb, h, h, MM, DD, 4 * DD);
  }

  hipLaunchKernelGGL(ln_f_k, dim3(MM), dim3(256), 0, stream, h, lnfw, lnfb, (float*)d_out);
}

// Round 5
// 2310.409 us; speedup vs baseline: 12.7602x; 1.2782x over previous
//
#include <hip/hip_runtime.h>
#include <math.h>

#define TT 1024
#define DD 1024
#define NH 16
#define NB 2
#define NL 12
#define RR 32
#define MM (NB * TT)  // 2048

typedef __attribute__((ext_vector_type(8))) short bf16x8;
typedef __attribute__((ext_vector_type(4))) float f32x4;

__device__ __forceinline__ unsigned short f2bf(float f) {
  unsigned int u = __float_as_uint(f);
  u = (u + 0x7FFFu + ((u >> 16) & 1u)) >> 16;
  return (unsigned short)u;
}

typedef __attribute__((address_space(1))) void gvoid;
typedef __attribute__((address_space(3))) void lvoid;
__device__ __forceinline__ void gload_lds16(const void* g, void* l) {
  __builtin_amdgcn_global_load_lds((gvoid*)g, (lvoid*)l, 16, 0, 0);
}

// ---------------------------------------------------------------- embed
__global__ __launch_bounds__(256) void embed_k(const int* __restrict__ ids,
                                               const float* __restrict__ wte,
                                               const float* __restrict__ wpe,
                                               float* __restrict__ h) {
  const int i = blockIdx.x * 256 + threadIdx.x;
  const int row = i >> 10;
  const int d = i & 1023;
  const int t = row & (TT - 1);
  const int id = ids[row];
  h[i] = wte[(size_t)id * DD + d] + wpe[(size_t)t * DD + d];
}

// ---------------------------------------------------------------- layernorm (fp32 in, bf16 out)
__global__ __launch_bounds__(256) void ln_bf_k(const float* __restrict__ x,
                                               const float* __restrict__ w,
                                               const float* __restrict__ b,
                                               unsigned short* __restrict__ out) {
  const int row = blockIdx.x;
  const float* xr = x + (size_t)row * DD;
  const float4 v = *(const float4*)(xr + threadIdx.x * 4);
  float s = v.x + v.y + v.z + v.w;
  float ss = v.x * v.x + v.y * v.y + v.z * v.z + v.w * v.w;
#pragma unroll
  for (int off = 32; off > 0; off >>= 1) {
    s += __shfl_down(s, off);
    ss += __shfl_down(ss, off);
  }
  __shared__ float rs[4], rss[4];
  const int wid = threadIdx.x >> 6;
  if ((threadIdx.x & 63) == 0) { rs[wid] = s; rss[wid] = ss; }
  __syncthreads();
  s = rs[0] + rs[1] + rs[2] + rs[3];
  ss = rss[0] + rss[1] + rss[2] + rss[3];
  const float mean = s * (1.f / DD);
  const float var = ss * (1.f / DD) - mean * mean;
  const float rstd = rsqrtf(var + 1e-5f);
  const float4 wv = *(const float4*)(w + threadIdx.x * 4);
  const float4 bv = *(const float4*)(b + threadIdx.x * 4);
  ushort4 o;
  o.x = f2bf((v.x - mean) * rstd * wv.x + bv.x);
  o.y = f2bf((v.y - mean) * rstd * wv.y + bv.y);
  o.z = f2bf((v.z - mean) * rstd * wv.z + bv.z);
  o.w = f2bf((v.w - mean) * rstd * wv.w + bv.w);
  *(ushort4*)(out + (size_t)row * DD + threadIdx.x * 4) = o;
}

// final layernorm fp32 out
__global__ __launch_bounds__(256) void ln_f_k(const float* __restrict__ x,
                                              const float* __restrict__ w,
                                              const float* __restrict__ b,
                                              float* __restrict__ out) {
  const int row = blockIdx.x;
  const float* xr = x + (size_t)row * DD;
  const float4 v = *(const float4*)(xr + threadIdx.x * 4);
  float s = v.x + v.y + v.z + v.w;
  float ss = v.x * v.x + v.y * v.y + v.z * v.z + v.w * v.w;
#pragma unroll
  for (int off = 32; off > 0; off >>= 1) {
    s += __shfl_down(s, off);
    ss += __shfl_down(ss, off);
  }
  __shared__ float rs[4], rss[4];
  const int wid = threadIdx.x >> 6;
  if ((threadIdx.x & 63) == 0) { rs[wid] = s; rss[wid] = ss; }
  __syncthreads();
  s = rs[0] + rs[1] + rs[2] + rs[3];
  ss = rss[0] + rss[1] + rss[2] + rss[3];
  const float mean = s * (1.f / DD);
  const float var = ss * (1.f / DD) - mean * mean;
  const float rstd = rsqrtf(var + 1e-5f);
  const float4 wv = *(const float4*)(w + threadIdx.x * 4);
  const float4 bv = *(const float4*)(b + threadIdx.x * 4);
  float4 o;
  o.x = (v.x - mean) * rstd * wv.x + bv.x;
  o.y = (v.y - mean) * rstd * wv.y + bv.y;
  o.z = (v.z - mean) * rstd * wv.z + bv.z;
  o.w = (v.w - mean) * rstd * wv.w + bv.w;
  *(float4*)(out + (size_t)row * DD + threadIdx.x * 4) = o;
}

// ---------------------------------------------------------------- LoRA fold, all layers in ONE launch
__global__ __launch_bounds__(256) void fusew_all_k(
    const float* __restrict__ aw, const float* __restrict__ ala, const float* __restrict__ alb,
    const float* __restrict__ pw, const float* __restrict__ pla, const float* __restrict__ plb,
    const float* __restrict__ fw, const float* __restrict__ fla, const float* __restrict__ flb,
    const float* __restrict__ mw, const float* __restrict__ mla, const float* __restrict__ mlb,
    unsigned short* __restrict__ oq, unsigned short* __restrict__ op_,
    unsigned short* __restrict__ of, unsigned short* __restrict__ om) {
  const int g = blockIdx.x;
  const int layer = g / 3072;
  const int lid = g - layer * 3072;
  const float *W, *Al, *Bl;
  unsigned short* out;
  int K, k0, n0;
  if (lid < 768) {
    W = aw + (size_t)layer * 3 * DD * DD;
    Al = ala + (size_t)layer * RR * DD;
    Bl = alb + (size_t)layer * 3 * DD * RR;
    out = oq + (size_t)layer * 3 * DD * DD;
    K = DD; k0 = (lid & 3) * 256; n0 = (lid >> 2) * 16;
  } else if (lid < 1024) {
    const int t = lid - 768;
    W = pw + (size_t)layer * DD * DD;
    Al = pla + (size_t)layer * RR * DD;
    Bl = plb + (size_t)layer * DD * RR;
    out = op_ + (size_t)layer * DD * DD;
    K = DD; k0 = (t & 3) * 256; n0 = (t >> 2) * 16;
  } else if (lid < 2048) {
    const int t = lid - 1024;
    W = fw + (size_t)layer * 4 * DD * DD;
    Al = fla + (size_t)layer * RR * DD;
    Bl = flb + (size_t)layer * 4 * DD * RR;
    out = of + (size_t)layer * 4 * DD * DD;
    K = DD; k0 = (t & 3) * 256; n0 = (t >> 2) * 16;
  } else {
    const int t = lid - 2048;
    W = mw + (size_t)layer * DD * 4 * DD;
    Al = mla + (size_t)layer * RR * 4 * DD;
    Bl = mlb + (size_t)layer * DD * RR;
    out = om + (size_t)layer * DD * 4 * DD;
    K = 4 * DD; k0 = (t & 15) * 256; n0 = (t >> 4) * 16;
  }
  __shared__ float As[32][260];
  const int tid = threadIdx.x;
#pragma unroll
  for (int i = 0; i < 8; ++i) {
    const int f4 = tid + i * 256;
    const int r = f4 >> 6;
    const int c = (f4 & 63) * 4;
    *(float4*)&As[r][c] = *(const float4*)(Al + (size_t)r * K + k0 + c);
  }
  const int nl = tid >> 4;
  const int kl = (tid & 15) * 4;
  float br[32];
  {
    const float* bp = Bl + (size_t)(n0 + nl) * RR;
#pragma unroll
    for (int r = 0; r < 32; r += 4) {
      const float4 v = *(const float4*)(bp + r);
      br[r] = 2.f * v.x; br[r + 1] = 2.f * v.y;
      br[r + 2] = 2.f * v.z; br[r + 3] = 2.f * v.w;
    }
  }
  float acc[16];
  const float* wp = W + (size_t)(n0 + nl) * K + k0;
#pragma unroll
  for (int j = 0; j < 4; ++j) {
    const float4 v = *(const float4*)(wp + kl + j * 64);
    acc[j * 4 + 0] = v.x; acc[j * 4 + 1] = v.y;
    acc[j * 4 + 2] = v.z; acc[j * 4 + 3] = v.w;
  }
  __syncthreads();
#pragma unroll
  for (int r = 0; r < 32; ++r) {
    const float bb = br[r];
#pragma unroll
    for (int j = 0; j < 4; ++j) {
      const float4 a = *(const float4*)&As[r][kl + j * 64];
      acc[j * 4 + 0] = fmaf(bb, a.x, acc[j * 4 + 0]);
      acc[j * 4 + 1] = fmaf(bb, a.y, acc[j * 4 + 1]);
      acc[j * 4 + 2] = fmaf(bb, a.z, acc[j * 4 + 2]);
      acc[j * 4 + 3] = fmaf(bb, a.w, acc[j * 4 + 3]);
    }
  }
  unsigned short* opp = out + (size_t)(n0 + nl) * K + k0;
#pragma unroll
  for (int j = 0; j < 4; ++j) {
    ushort4 u;
    u.x = f2bf(acc[j * 4 + 0]); u.y = f2bf(acc[j * 4 + 1]);
    u.z = f2bf(acc[j * 4 + 2]); u.w = f2bf(acc[j * 4 + 3]);
    *(ushort4*)(opp + kl + j * 64) = u;
  }
}

// ---------------------------------------------------------------- unified bf16 MFMA GEMM
// BK=64, 4 waves (2x2), XOR-swizzled LDS (pre-swizzled global src + swizzled read).
// MODE 1: fp32 out = acc+bias+res; MODE 2: gelu->bf16; MODE 3: qkv split.
template <int BMt, int BNt, int MODE>
__global__ __launch_bounds__(256) void gemm_t(const unsigned short* __restrict__ A,
                                              const unsigned short* __restrict__ Wt,
                                              const float* __restrict__ bias,
                                              const float* __restrict__ res,
                                              float* __restrict__ Cf,
                                              unsigned short* __restrict__ Cb,
                                              unsigned short* __restrict__ vt,
                                              int M, int N, int K) {
  constexpr int BKt = 64;
  constexpr int MI2 = BMt / 32, NJ2 = BNt / 32;
  constexpr int CA = BMt / 32;  // 1KB chunks per wave for A
  constexpr int CB = BNt / 32;
  __shared__ unsigned short As[BMt * BKt];
  __shared__ unsigned short Bs[BNt * BKt];
  const int tid = threadIdx.x;
  const int w = tid >> 6, l = tid & 63;
  const int bm = blockIdx.y * BMt, bn = blockIdx.x * BNt;
  const int wr = w >> 1, wc = w & 1;
  const int lr16 = l & 15, lg = l >> 4, l7 = l & 7;
  const int crow = l >> 3;                       // row within 8-row chunk
  const int csrc = ((l & 7) ^ (crow & 7)) * 8;   // pre-swizzled col (elements)
  f32x4 acc[MI2][NJ2] = {};
  for (int k0 = 0; k0 < K; k0 += BKt) {
    __syncthreads();
#pragma unroll
    for (int i = 0; i < CA; ++i) {
      const int ch = w * CA + i;
      gload_lds16(A + (size_t)(bm + ch * 8 + crow) * K + k0 + csrc,
                  (char*)As + ch * 1024);
    }
#pragma unroll
    for (int i = 0; i < CB; ++i) {
      const int ch = w * CB + i;
      gload_lds16(Wt + (size_t)(bn + ch * 8 + crow) * K + k0 + csrc,
                  (char*)Bs + ch * 1024);
    }
    __syncthreads();
    bf16x8 af[MI2][2], bfr[NJ2][2];
#pragma unroll
    for (int mi = 0; mi < MI2; ++mi)
#pragma unroll
      for (int kk = 0; kk < 2; ++kk)
        af[mi][kk] = *(const bf16x8*)((const char*)As +
            (wr * (BMt / 2) + mi * 16 + lr16) * 128 + (((kk * 4 + lg) ^ l7) * 16));
#pragma unroll
    for (int nj = 0; nj < NJ2; ++nj)
#pragma unroll
      for (int kk = 0; kk < 2; ++kk)
        bfr[nj][kk] = *(const bf16x8*)((const char*)Bs +
            (wc * (BNt / 2) + nj * 16 + lr16) * 128 + (((kk * 4 + lg) ^ l7) * 16));
#pragma unroll
    for (int kk = 0; kk < 2; ++kk)
#pragma unroll
      for (int mi = 0; mi < MI2; ++mi)
#pragma unroll
        for (int nj = 0; nj < NJ2; ++nj)
          acc[mi][nj] = __builtin_amdgcn_mfma_f32_16x16x32_bf16(
              af[mi][kk], bfr[nj][kk], acc[mi][nj], 0, 0, 0);
  }
  const int cr = lg * 4;
  const int cc = lr16;
#pragma unroll
  for (int mi = 0; mi < MI2; ++mi) {
    const int gr0 = bm + wr * (BMt / 2) + mi * 16 + cr;
#pragma unroll
    for (int nj = 0; nj < NJ2; ++nj) {
      const int gc = bn + wc * (BNt / 2) + nj * 16 + cc;
      const float bv = bias[gc];
      if (MODE == 3) {
        if (gc < 2048) {
#pragma unroll
          for (int r = 0; r < 4; ++r)
            Cb[(size_t)(gr0 + r) * 2048 + gc] = f2bf(acc[mi][nj][r] + bv);
        } else {
          const int hv = gc - 2048;
          const int b_ = gr0 >> 10, t0 = gr0 & 1023;
          ushort4 u;
          u.x = f2bf(acc[mi][nj][0] + bv); u.y = f2bf(acc[mi][nj][1] + bv);
          u.z = f2bf(acc[mi][nj][2] + bv); u.w = f2bf(acc[mi][nj][3] + bv);
          *(ushort4*)(vt + ((size_t)(b_ * 1024 + hv)) * 1024 + t0) = u;
        }
      } else if (MODE == 1) {
#pragma unroll
        for (int r = 0; r < 4; ++r) {
          const size_t idx = (size_t)(gr0 + r) * N + gc;
          Cf[idx] = acc[mi][nj][r] + bv + res[idx];
        }
      } else {  // MODE 2
#pragma unroll
        for (int r = 0; r < 4; ++r) {
          float v = acc[mi][nj][r] + bv;
          v = 0.5f * v * (1.f + erff(v * 0.70710678118654752f));
          Cb[(size_t)(gr0 + r) * N + gc] = f2bf(v);
        }
      }
    }
  }
}

// ---------------------------------------------------------------- MFMA flash attention
// qk bf16 [B*T, 2048] (Q | K per head), vt bf16 [B*H, 64, T], out bf16 [B*T, 1024]
#define SM_SCALE_LOG2E 0.18033688011112042f  // log2(e)/8
__global__ __launch_bounds__(256) void attn3_k(const unsigned short* __restrict__ qk,
                                               const unsigned short* __restrict__ vt,
                                               unsigned short* __restrict__ out) {
  const int qt = blockIdx.x;
  const int bh = blockIdx.y;
  const int b = bh >> 4, hh = bh & 15;
  const int tid = threadIdx.x;
  const int w = tid >> 6, l = tid & 63;
  const int lg = l >> 4;
  const int lr = l & 15;

  __shared__ unsigned short Kt[2][64 * 64];
  __shared__ unsigned short Vb[2][64 * 64];
  __shared__ unsigned short Pb[4][16 * 64];

  bf16x8 qf[2];
  {
    const unsigned short* qp =
        qk + ((size_t)(b * TT + qt * 64 + w * 16 + lr)) * 2048 + hh * 64 + lg * 8;
    qf[0] = *(const bf16x8*)(qp);
    qf[1] = *(const bf16x8*)(qp + 32);
  }
  f32x4 oacc[4] = {};
  float mrow[4] = {-1e30f, -1e30f, -1e30f, -1e30f};
  float lrow[4] = {0.f, 0.f, 0.f, 0.f};

  auto stage = [&](int buf, int kt) {
#pragma unroll
    for (int oo = 0; oo < 2; ++oo) {
      const int o = w + oo * 4;
      const int row = o * 8 + (l >> 3);
      const int sc = ((l & 7) ^ (l >> 3)) * 8;
      const unsigned short* ks =
          qk + ((size_t)(b * TT + kt * 64 + row)) * 2048 + 1024 + hh * 64 + sc;
      gload_lds16(ks, (char*)&Kt[buf][0] + o * 1024);
      const unsigned short* vs =
          vt + ((size_t)(bh * 64 + row)) * 1024 + kt * 64 + sc;
      gload_lds16(vs, (char*)&Vb[buf][0] + o * 1024);
    }
  };

  stage(0, 0);
  int cur = 0;
  unsigned short* Pw = &Pb[w][0];
  const int qlocal = w * 16 + lg * 4;

  for (int kt = 0; kt <= qt; ++kt) {
    __syncthreads();
    if (kt < qt) stage(cur ^ 1, kt + 1);
    const unsigned short* Kb_ = &Kt[cur][0];
    const unsigned short* Vb_ = &Vb[cur][0];
    const int effc = lr & 7;

    f32x4 s[4];
#pragma unroll
    for (int j = 0; j < 4; ++j) {
      f32x4 sj = {};
#pragma unroll
      for (int ks = 0; ks < 2; ++ks) {
        const bf16x8 kf = *(const bf16x8*)((const char*)Kb_ + (j * 16 + lr) * 128 +
                                           (((ks * 4 + lg) ^ effc) * 16));
        sj = __builtin_amdgcn_mfma_f32_16x16x32_bf16(qf[ks], kf, sj, 0, 0, 0);
      }
      s[j] = sj;
    }

    const bool last = (kt == qt);
    float tv[4][4];
#pragma unroll
    for (int j = 0; j < 4; ++j)
#pragma unroll
      for (int r = 0; r < 4; ++r) {
        float v = s[j][r] * SM_SCALE_LOG2E;
        if (last && (j * 16 + lr > qlocal + r)) v = -1e30f;
        tv[j][r] = v;
      }
    float corr[4];
#pragma unroll
    for (int r = 0; r < 4; ++r) {
      float mx = fmaxf(fmaxf(tv[0][r], tv[1][r]), fmaxf(tv[2][r], tv[3][r]));
      mx = fmaxf(mx, __shfl_xor(mx, 1));
      mx = fmaxf(mx, __shfl_xor(mx, 2));
      mx = fmaxf(mx, __shfl_xor(mx, 4));
      mx = fmaxf(mx, __shfl_xor(mx, 8));
      const float mn = fmaxf(mrow[r], mx);
      corr[r] = exp2f(mrow[r] - mn);
      mrow[r] = mn;
      lrow[r] *= corr[r];
    }
#pragma unroll
    for (int dt = 0; dt < 4; ++dt) {
      oacc[dt][0] *= corr[0]; oacc[dt][1] *= corr[1];
      oacc[dt][2] *= corr[2]; oacc[dt][3] *= corr[3];
    }
#pragma unroll
    for (int j = 0; j < 4; ++j)
#pragma unroll
      for (int r = 0; r < 4; ++r) {
        const float p = exp2f(tv[j][r] - mrow[r]);
        lrow[r] += p;
        const int q = lg * 4 + r;
        const int kv = j * 16 + lr;
        *(unsigned short*)((char*)Pw + q * 128 + ((kv * 2) ^ ((q & 7) << 4))) = f2bf(p);
      }
    asm volatile("s_waitcnt lgkmcnt(0)" ::: "memory");
    __builtin_amdgcn_sched_barrier(0);

#pragma unroll
    for (int ks = 0; ks < 2; ++ks) {
      const bf16x8 pf = *(const bf16x8*)((const char*)Pw + lr * 128 +
                                         (((ks * 4 + lg) ^ effc) * 16));
#pragma unroll
      for (int dt = 0; dt < 4; ++dt) {
        const bf16x8 vf = *(const bf16x8*)((const char*)Vb_ + (dt * 16 + lr) * 128 +
                                           (((ks * 4 + lg) ^ effc) * 16));
        oacc[dt] = __builtin_amdgcn_mfma_f32_16x16x32_bf16(pf, vf, oacc[dt], 0, 0, 0);
      }
    }
    cur ^= 1;
  }

#pragma unroll
  for (int r = 0; r < 4; ++r) {
    float lv = lrow[r];
    lv += __shfl_xor(lv, 1);
    lv += __shfl_xor(lv, 2);
    lv += __shfl_xor(lv, 4);
    lv += __shfl_xor(lv, 8);
    lrow[r] = 1.f / lv;
  }
  unsigned short* ob = out + ((size_t)(b * TT + qt * 64 + w * 16 + lg * 4)) * 1024 + hh * 64 + lr;
#pragma unroll
  for (int r = 0; r < 4; ++r)
#pragma unroll
    for (int dt = 0; dt < 4; ++dt)
      ob[(size_t)r * 1024 + dt * 16] = f2bf(oacc[dt][r] * lrow[r]);
}

// ---------------------------------------------------------------- host
extern "C" void kernel_launch(void* const* d_in, const int* in_sizes, int n_in,
                              void* d_out, int out_size, void* d_ws, size_t ws_size,
                              hipStream_t stream) {
  (void)in_sizes; (void)n_in; (void)out_size; (void)ws_size;
  const int* ids = (const int*)d_in[0];
  const float* wte = (const float*)d_in[1];
  const float* wpe = (const float*)d_in[2];
  const float* ln1w = (const float*)d_in[3];
  const float* ln1b = (const float*)d_in[4];
  const float* attnw = (const float*)d_in[5];
  const float* attnb = (const float*)d_in[6];
  const float* attnla = (const float*)d_in[7];
  const float* attnlb = (const float*)d_in[8];
  const float* projw = (const float*)d_in[9];
  const float* projb = (const float*)d_in[10];
  const float* projla = (const float*)d_in[11];
  const float* projlb = (const float*)d_in[12];
  const float* ln2w = (const float*)d_in[13];
  const float* ln2b = (const float*)d_in[14];
  const float* fcw = (const float*)d_in[15];
  const float* fcb = (const float*)d_in[16];
  const float* fcla = (const float*)d_in[17];
  const float* fclb = (const float*)d_in[18];
  const float* mpw = (const float*)d_in[19];
  const float* mpb = (const float*)d_in[20];
  const float* mpla = (const float*)d_in[21];
  const float* mplb = (const float*)d_in[22];
  const float* lnfw = (const float*)d_in[23];
  const float* lnfb = (const float*)d_in[24];

  char* ws = (char*)d_ws;
  float* h = (float*)ws;                        ws += (size_t)MM * DD * 4;       // 8MB
  unsigned short* x = (unsigned short*)ws;      ws += (size_t)MM * DD * 2;       // 4MB
  unsigned short* qkb = (unsigned short*)ws;    ws += (size_t)MM * 2 * DD * 2;   // 8MB
  unsigned short* vtb = (unsigned short*)ws;    ws += (size_t)MM * DD * 2;       // 4MB
  unsigned short* ho = (unsigned short*)ws;     ws += (size_t)MM * DD * 2;       // 4MB
  unsigned short* hm = (unsigned short*)ws;     ws += (size_t)MM * 4 * DD * 2;   // 16MB
  unsigned short* wqkvA = (unsigned short*)ws;  ws += (size_t)NL * 3 * DD * DD * 2;  // 72MB
  unsigned short* wprojA = (unsigned short*)ws; ws += (size_t)NL * DD * DD * 2;      // 24MB
  unsigned short* wfcA = (unsigned short*)ws;   ws += (size_t)NL * 4 * DD * DD * 2;  // 96MB
  unsigned short* wmpA = (unsigned short*)ws;   ws += (size_t)NL * DD * 4 * DD * 2;  // 96MB

  hipLaunchKernelGGL(embed_k, dim3(MM * DD / 256), dim3(256), 0, stream, ids, wte, wpe, h);

  hipLaunchKernelGGL(fusew_all_k, dim3(NL * 3072), dim3(256), 0, stream,
                     attnw, attnla, attnlb, projw, projla, projlb,
                     fcw, fcla, fclb, mpw, mpla, mplb,
                     wqkvA, wprojA, wfcA, wmpA);

  for (int l = 0; l < NL; ++l) {
    const float* ab = attnb + (size_t)l * 3 * DD;
    const float* pb = projb + (size_t)l * DD;
    const float* fb = fcb + (size_t)l * 4 * DD;
    const float* mb = mpb + (size_t)l * DD;
    const unsigned short* wqkv = wqkvA + (size_t)l * 3 * DD * DD;
    const unsigned short* wproj = wprojA + (size_t)l * DD * DD;
    const unsigned short* wfc = wfcA + (size_t)l * 4 * DD * DD;
    const unsigned short* wmp = wmpA + (size_t)l * DD * 4 * DD;

    // x = LN1(h)
    hipLaunchKernelGGL(ln_bf_k, dim3(MM), dim3(256), 0, stream, h,
                       ln1w + (size_t)l * DD, ln1b + (size_t)l * DD, x);
    // qkv = x @ wqkv^T + ab -> qkb (Q,K) + vtb (V transposed)
    hipLaunchKernelGGL((gemm_t<128, 64, 3>), dim3(3 * DD / 64, MM / 128), dim3(256), 0,
                       stream, x, wqkv, ab, (const float*)nullptr, (float*)nullptr,
                       qkb, vtb, MM, 3 * DD, DD);
    // o = attention
    hipLaunchKernelGGL(attn3_k, dim3(TT / 64, NB * NH), dim3(256), 0, stream, qkb, vtb, ho);
    // h = h + o @ wproj^T + pb
    hipLaunchKernelGGL((gemm_t<64, 64, 1>), dim3(DD / 64, MM / 64), dim3(256), 0,
                       stream, ho, wproj, pb, h, h, (unsigned short*)nullptr,
                       (unsigned short*)nullptr, MM, DD, DD);
    // x = LN2(h)
    hipLaunchKernelGGL(ln_bf_k, dim3(MM), dim3(256), 0, stream, h,
                       ln2w + (size_t)l * DD, ln2b + (size_t)l * DD, x);
    // m = gelu(x @ wfc^T + fb)
    hipLaunchKernelGGL((gemm_t<128, 64, 2>), dim3(4 * DD / 64, MM / 128), dim3(256), 0,
                       stream, x, wfc, fb, (const float*)nullptr, (float*)nullptr, hm,
                       (unsigned short*)nullptr, MM, 4 * DD, DD);
    // h = h + m @ wmp^T + mb
    hipLaunchKernelGGL((gemm_t<64, 64, 1>), dim3(DD / 64, MM / 64), dim3(256), 0,
                       stream, hm, wmp, mb, h, h, (unsigned short*)nullptr,
                       (unsigned short*)nullptr, MM, DD, 4 * DD);
  }

  hipLaunchKernelGGL(ln_f_k, dim3(MM), dim3(256), 0, stream, h, lnfw, lnfb, (float*)d_out);
}